// Round 16
// baseline (1170.902 us; speedup 1.0000x reference)
//
#include <hip/hip_runtime.h>

typedef __bf16 bf16;
typedef __bf16 bf16x8 __attribute__((ext_vector_type(8)));
typedef __bf16 bf16x4 __attribute__((ext_vector_type(4)));
typedef float f32x4 __attribute__((ext_vector_type(4)));
typedef unsigned short u16x4 __attribute__((ext_vector_type(4)));
typedef __attribute__((address_space(3))) const void as3_void;
typedef __attribute__((address_space(3))) const char as3_char;

#define GLOAD16(G,L) __builtin_amdgcn_global_load_lds((__attribute__((address_space(1))) const void*)(G), (__attribute__((address_space(3))) void*)(L), 16, 0, 0)

// ---------------- conversion kernels ----------------
__global__ void k_cvt_bf16(const float* __restrict__ src, bf16* __restrict__ dst, int n4){
  int i = blockIdx.x*256 + threadIdx.x;
  if (i < n4){
    float4 v = reinterpret_cast<const float4*>(src)[i];
    bf16x4 o; o[0]=(bf16)v.x; o[1]=(bf16)v.y; o[2]=(bf16)v.z; o[3]=(bf16)v.w;
    reinterpret_cast<bf16x4*>(dst)[i] = o;
  }
}

// src: K x N (f32) -> dst: N x K (bf16)
__global__ void k_transpose_cvt(const float* __restrict__ src, bf16* __restrict__ dst, int K, int N){
  __shared__ float tile[32][33];
  int n0 = blockIdx.x*32, k0 = blockIdx.y*32;
  int tx = threadIdx.x & 31, ty = threadIdx.x >> 5; // 32 x 8
  #pragma unroll
  for (int i=0;i<32;i+=8)
    tile[ty+i][tx] = src[(size_t)(k0+ty+i)*N + n0+tx];
  __syncthreads();
  #pragma unroll
  for (int i=0;i<32;i+=8)
    dst[(size_t)(n0+ty+i)*K + k0+tx] = (bf16)tile[tx][ty+i];
}

// ---------------- 256x256 bf16 MFMA GEMM, 8 waves, BK=64, 4-phase K-tile schedule ----------------
template<int EPI>
__global__ __launch_bounds__(512,2) void k_gemm8(
    const bf16* __restrict__ A, const bf16* __restrict__ Bt,
    const float* __restrict__ bias, int N, int K,
    bf16* __restrict__ q_out, bf16* __restrict__ k_out, bf16* __restrict__ v_out,
    float* __restrict__ c_out)
{
  __shared__ bf16 S[2][4][8192];   // [buf][A0,A1,B0,B1][128*64]
  const int t = threadIdx.x, w = t>>6, l = t&63, g = l>>4, c = l&15;
  const int wm = w>>2, wn = w&3;   // 2M x 4N waves
  const int nb = N>>8;
  const int cpx = gridDim.x>>3;
  const int swz = (blockIdx.x&7)*cpx + (blockIdx.x>>3);   // XCD swizzle (grid%8==0)
  const int m0 = (swz/nb)<<8, n0 = (swz%nb)<<8;
  const int NK = K>>6;

  int abase[2];
  #pragma unroll
  for (int kk=0; kk<2; ++kk)
    abase[kk] = (c<<7) + (((((kk<<2)|g)) ^ (c&7))<<4);

  const int r0 = t>>3;
  const int col0 = ((t&7) ^ (r0&7))<<3;

  auto stageA = [&](int kt2){
    #pragma unroll
    for (int hh=0; hh<2; ++hh){
      const bf16* sp = A + (size_t)(m0 + hh*128)*K + (kt2<<6);
      char* dp = (char*)&S[kt2&1][hh][0];
      GLOAD16(sp + (size_t)r0*K + col0,      dp + t*16);
      GLOAD16(sp + (size_t)(r0+64)*K + col0, dp + (t+512)*16);
    }
  };
  auto stageB = [&](int kt2){
    #pragma unroll
    for (int hh=0; hh<2; ++hh){
      const bf16* sp = Bt + (size_t)(n0 + hh*128)*K + (kt2<<6);
      char* dp = (char*)&S[kt2&1][2+hh][0];
      GLOAD16(sp + (size_t)r0*K + col0,      dp + t*16);
      GLOAD16(sp + (size_t)(r0+64)*K + col0, dp + (t+512)*16);
    }
  };

  f32x4 acc[8][4] = {};

  stageA(0); stageB(0);
  asm volatile("s_waitcnt vmcnt(0)" ::: "memory");
  __builtin_amdgcn_s_barrier();

  for (int kt=0; kt<NK; ++kt){
    const int bufc = kt&1;
    const char* Ab_ = (const char*)&S[bufc][wm][0];
    const char* Bb_ = (const char*)&S[bufc][2+(wn>>1)][0] + ((wn&1)<<13);
    const bool pre = (kt+1 < NK);
    bf16x8 af[4][2], bfr[2][2];

    auto lda = [&](int mh){
      #pragma unroll
      for (int mf=0; mf<4; ++mf)
        #pragma unroll
        for (int kk=0; kk<2; ++kk)
          af[mf][kk] = *reinterpret_cast<const bf16x8*>(Ab_ + abase[kk] + mh*8192 + mf*2048);
    };
    auto ldb = [&](int nh){
      #pragma unroll
      for (int nf=0; nf<2; ++nf)
        #pragma unroll
        for (int kk=0; kk<2; ++kk)
          bfr[nf][kk] = *reinterpret_cast<const bf16x8*>(Bb_ + abase[kk] + nh*4096 + nf*2048);
    };
    auto cluster = [&](int mh, int nh){
      __builtin_amdgcn_s_barrier();
      asm volatile("s_waitcnt lgkmcnt(0)" ::: "memory");
      __builtin_amdgcn_sched_barrier(0);
      __builtin_amdgcn_s_setprio(1);
      #pragma unroll
      for (int mf=0; mf<4; ++mf)
        #pragma unroll
        for (int nf=0; nf<2; ++nf)
          #pragma unroll
          for (int kk=0; kk<2; ++kk)
            acc[mh*4+mf][nh*2+nf] =
              __builtin_amdgcn_mfma_f32_16x16x32_bf16(af[mf][kk], bfr[nf][kk], acc[mh*4+mf][nh*2+nf], 0,0,0);
      __builtin_amdgcn_s_setprio(0);
    };

    lda(0); ldb(0);
    if (pre) stageA(kt+1);
    cluster(0,0);
    __builtin_amdgcn_s_barrier();
    ldb(1);
    if (pre) stageB(kt+1);
    cluster(0,1);
    __builtin_amdgcn_s_barrier();
    lda(1);
    cluster(1,1);
    __builtin_amdgcn_s_barrier();
    ldb(0);
    cluster(1,0);
    asm volatile("s_waitcnt vmcnt(0)" ::: "memory");
    __builtin_amdgcn_s_barrier();
  }

  if constexpr (EPI==0){
    #pragma unroll
    for (int NF=0; NF<4; ++NF){
      const int col = n0 + wn*64 + NF*16 + c;
      const int sec = col>>11; const int rem = col&2047;
      const int hhd = rem>>7;  const int dd = rem&127;
      bf16* dst = (sec==0) ? q_out : ((sec==1) ? k_out : v_out);
      const float bv = bias[col];
      const float qs = (sec==0) ? 0.12751743f : 1.0f;  // pre-scale Q: 1/sqrt(128)*log2(e)
      #pragma unroll
      for (int MF=0; MF<8; ++MF)
        #pragma unroll
        for (int ri=0; ri<4; ++ri){
          const int row = m0 + wm*128 + MF*16 + (g<<2) + ri;
          const int bb = row>>10, qp = row&1023;
          dst[(((size_t)(bb*16+hhd)*1024 + qp)<<7) + dd] = (bf16)((acc[MF][NF][ri] + bv)*qs);
        }
    }
  } else {
    #pragma unroll
    for (int NF=0; NF<4; ++NF){
      const int col = n0 + wn*64 + NF*16 + c;
      const float bv = bias[col];
      #pragma unroll
      for (int MF=0; MF<8; ++MF)
        #pragma unroll
        for (int ri=0; ri<4; ++ri){
          const int row = m0 + wm*128 + MF*16 + (g<<2) + ri;
          c_out[(size_t)row*N + col] = acc[MF][NF][ri] + bv;
        }
    }
  }
}

// 2 x ds_read_b64_tr_b16 with literal offsets from the single per-tile V base (vbL, LDS addr-space)
#define TRRD(R0, R1, O0, O1) \
  asm volatile("ds_read_b64_tr_b16 %0, %2 offset:" O0 "\n\t" \
               "ds_read_b64_tr_b16 %1, %2 offset:" O1 \
               : "=&v"(R0), "=&v"(R1) : "v"(vbL) : "memory")

// ---------------- fused paged + causal flash attention ----------------
// r15 structure; CHANGE (T14 async-STAGE split): paged tiles issue their 8 float4 loads
// BEFORE process(T) (HBM/L2 latency hides under QK+softmax+PV), cvt+ds_write AFTER.
__global__ __launch_bounds__(512) __attribute__((amdgpu_waves_per_eu(4,4))) void k_attn(
    const bf16* __restrict__ qb, const bf16* __restrict__ kb, const bf16* __restrict__ vb,
    const float* __restrict__ kpf, const float* __restrict__ vpf,
    const int* __restrict__ page_pos, const int* __restrict__ input_pos,
    bf16* __restrict__ ctx)
{
  __shared__ bf16 Ks[2*64*128];
  __shared__ bf16 Vs[2*64*128];
  const int t = threadIdx.x, w = t>>6, l = t&63, g = l>>4, c = l&15;
  const int bid = blockIdx.x;
  const int wg = (bid&7)*128 + (bid>>3);
  const int qt = wg & 7, h = (wg>>3)&15, b = wg>>7;
  const int q0w = (qt<<7) + (w<<4);
  const size_t bh = (size_t)(b*16 + h);

  const bf16* qptr = qb + (bh<<17);
  bf16x8 qf[4];
  #pragma unroll
  for (int kc=0;kc<4;kc++)
    qf[kc] = *reinterpret_cast<const bf16x8*>(qptr + ((size_t)(q0w + c)<<7) + kc*32 + (g<<3));

  int kbase[4];
  #pragma unroll
  for (int kc=0;kc<4;kc++)
    kbase[kc] = (c<<8) + ((((kc<<2)|g) ^ c)<<4);
  const int voffL = (g<<11) + (c<<3);   // V tr_read base offset

  // causal staging (gload_lds, 16B slots, 2/thread)
  int kOff[2], vOff[2];
  #pragma unroll
  for (int j=0;j<2;j++){
    const int slot = t + (j<<9);
    {
      const int a = slot<<4; const int r = a>>8; const int co = (a&255) ^ ((r&15)<<4);
      kOff[j] = (r<<7) + (co>>1);
    }
    {
      const int s_ = slot;
      const int p  = ((s_>>6)<<2) | ((s_>>1)&3);
      const int d0 = (((s_>>3)&7)<<4) | ((s_&1)<<3);
      const int pp = (p&32) | ((p&4)<<2) | (((p>>3)&3)<<2) | (p&3); // pi(p)
      vOff[j] = (pp<<7) + d0;
    }
  }
  // paged reg-staging (f32 source, 8B dest units, 4/thread): same maps at half granularity
  int ksrc[4], vsrc[4];
  #pragma unroll
  for (int j=0;j<4;j++){
    const int uu = t + (j<<9);        // 8B dest unit, dest byte = uu*8
    const int s_ = uu>>1, hh = uu&1;
    {
      const int a = s_<<4; const int r = a>>8; const int co = (a&255) ^ ((r&15)<<4);
      ksrc[j] = (r<<7) + (co>>1) + (hh<<2);
    }
    {
      const int p  = ((s_>>6)<<2) | ((s_>>1)&3);
      const int d0 = (((s_>>3)&7)<<4) | ((s_&1)<<3);
      const int pp = (p&32) | ((p&4)<<2) | (((p>>3)&3)<<2) | (p&3);
      vsrc[j] = (pp<<7) + d0 + (hh<<2);
    }
  }
  const bf16* kcb = kb + (bh<<17);
  const bf16* vcb = vb + (bh<<17);
  const int len_b = input_pos[b*2+1];
  const int NT = 32 + ((qt+1)<<1);

  f32x4 o[8] = {};
  float mrow = -1e38f;
  float lsum = 0.f;

  auto stage_causal = [&](int T, int buf){
    const int kt = T-32;
    const bf16* ks  = kcb + ((size_t)kt<<13);
    const bf16* vs_ = vcb + ((size_t)kt<<13);
    char* kd = (char*)Ks + (buf<<14) + (w<<10);
    char* vd = (char*)Vs + (buf<<14) + (w<<10);
    #pragma unroll
    for (int j=0;j<2;j++){
      GLOAD16(ks  + kOff[j], kd + (j<<13));
      GLOAD16(vs_ + vOff[j], vd + (j<<13));
    }
  };
  auto stage_paged_full = [&](int T, int buf){
    const size_t pb  = ((((size_t)(T>>2)<<3) + (size_t)b)*16 + (size_t)h) << 15;
    const size_t off = (size_t)(T&3)<<13;
    const float* kp = kpf + pb + off;
    const float* vp = vpf + pb + off;
    float4 kr[4], vr_[4];
    #pragma unroll
    for (int j=0;j<4;j++) kr[j]  = *reinterpret_cast<const float4*>(kp + ksrc[j]);
    #pragma unroll
    for (int j=0;j<4;j++) vr_[j] = *reinterpret_cast<const float4*>(vp + vsrc[j]);
    char* kd = (char*)Ks + (buf<<14);
    char* vd = (char*)Vs + (buf<<14);
    #pragma unroll
    for (int j=0;j<4;j++){
      bf16x4 o4; o4[0]=(bf16)kr[j].x; o4[1]=(bf16)kr[j].y; o4[2]=(bf16)kr[j].z; o4[3]=(bf16)kr[j].w;
      *reinterpret_cast<bf16x4*>(kd + ((t + (j<<9))<<3)) = o4;
    }
    #pragma unroll
    for (int j=0;j<4;j++){
      bf16x4 o4; o4[0]=(bf16)vr_[j].x; o4[1]=(bf16)vr_[j].y; o4[2]=(bf16)vr_[j].z; o4[3]=(bf16)vr_[j].w;
      *reinterpret_cast<bf16x4*>(vd + ((t + (j<<9))<<3)) = o4;
    }
  };

  auto process = [&](int buf, int lo, int hi, bool masked, bool causal, int ktg){
    const char* Kb = (const char*)Ks + (buf<<14);
    as3_char* vbL = (as3_char*)((as3_char*)Vs + (buf<<14) + voffL);
    f32x4 s[4] = {};
    #pragma unroll
    for (int kc=0;kc<4;kc++){
      const char* bk = Kb + kbase[kc];
      bf16x8 kf[4];
      #pragma unroll
      for (int cb=0;cb<4;cb++)
        kf[cb] = *reinterpret_cast<const bf16x8*>(bk + (cb<<12));
      __builtin_amdgcn_s_setprio(1);
      #pragma unroll
      for (int cb=0;cb<4;cb++)
        s[cb] = __builtin_amdgcn_mfma_f32_16x16x32_bf16(kf[cb], qf[kc], s[cb], 0,0,0);
      __builtin_amdgcn_s_setprio(0);
    }
    if (masked){
      #pragma unroll
      for (int cb=0;cb<4;cb++)
        #pragma unroll
        for (int ri=0;ri<4;ri++){
          const int kvl = (cb<<4) + (g<<2) + ri;
          bool ok = (kvl >= lo) && (kvl < hi);
          if (causal) ok = ok && ((ktg + kvl) <= (q0w + c));
          s[cb][ri] = ok ? s[cb][ri] : -3e38f;
        }
    }
    {
      float m0_ = fmaxf(fmaxf(s[0][0], s[0][1]), fmaxf(s[0][2], s[0][3]));
      float m1_ = fmaxf(fmaxf(s[1][0], s[1][1]), fmaxf(s[1][2], s[1][3]));
      float m2_ = fmaxf(fmaxf(s[2][0], s[2][1]), fmaxf(s[2][2], s[2][3]));
      float m3_ = fmaxf(fmaxf(s[3][0], s[3][1]), fmaxf(s[3][2], s[3][3]));
      float mx = fmaxf(fmaxf(m0_, m1_), fmaxf(m2_, m3_));
      const int defer = __all(mx - mrow <= 11.5f);
      if (!defer){
        float mr = fmaxf(mx, __shfl_xor(mx, 16, 64));
        mr = fmaxf(mr, __shfl_xor(mr, 32, 64));
        const float mn = fmaxf(mrow, mr);
        const float al = exp2f(mrow - mn);
        mrow = mn;
        lsum *= al;
        #pragma unroll
        for (int ri=0;ri<4;ri++){
          const float av = __shfl(al, (l&48) | ((g<<2)+ri), 64);
          #pragma unroll
          for (int dcb=0;dcb<8;dcb++) o[dcb][ri] *= av;
        }
      }
      float ps = 0.f;
      #pragma unroll
      for (int cb=0;cb<4;cb++)
        #pragma unroll
        for (int ri=0;ri<4;ri++){
          const float e = exp2f(s[cb][ri] - mrow);
          s[cb][ri] = e; ps += e;
        }
      lsum += ps;
    }
    // PV: single-base literal-offset tr_reads, batched 4-at-a-time per MFMA cluster
    {
      u16x4 vr0[4], vr1[4];
      bf16x8 pav;
      union { unsigned short us[8]; bf16x8 v; } uu;
      #pragma unroll
      for (int e=0;e<8;e++) pav[e] = (bf16)s[e>>2][e&3];
      TRRD(vr0[0],vr1[0],"0","1024");  TRRD(vr0[1],vr1[1],"128","1152");
      TRRD(vr0[2],vr1[2],"256","1280");TRRD(vr0[3],vr1[3],"384","1408");
      asm volatile("s_waitcnt lgkmcnt(0)" ::: "memory");
      __builtin_amdgcn_sched_barrier(0);
      __builtin_amdgcn_s_setprio(1);
      #pragma unroll
      for (int d4=0;d4<4;d4++){
        #pragma unroll
        for (int i=0;i<4;i++){ uu.us[i]=vr0[d4][i]; uu.us[4+i]=vr1[d4][i]; }
        o[d4] = __builtin_amdgcn_mfma_f32_16x16x32_bf16(pav, uu.v, o[d4], 0,0,0);
      }
      __builtin_amdgcn_s_setprio(0);
      TRRD(vr0[0],vr1[0],"512","1536");  TRRD(vr0[1],vr1[1],"640","1664");
      TRRD(vr0[2],vr1[2],"768","1792");  TRRD(vr0[3],vr1[3],"896","1920");
      asm volatile("s_waitcnt lgkmcnt(0)" ::: "memory");
      __builtin_amdgcn_sched_barrier(0);
      __builtin_amdgcn_s_setprio(1);
      #pragma unroll
      for (int d4=0;d4<4;d4++){
        #pragma unroll
        for (int i=0;i<4;i++){ uu.us[i]=vr0[d4][i]; uu.us[4+i]=vr1[d4][i]; }
        o[4+d4] = __builtin_amdgcn_mfma_f32_16x16x32_bf16(pav, uu.v, o[4+d4], 0,0,0);
      }
      __builtin_amdgcn_s_setprio(0);
      #pragma unroll
      for (int e=0;e<8;e++) pav[e] = (bf16)s[2+(e>>2)][e&3];
      TRRD(vr0[0],vr1[0],"8192","9216"); TRRD(vr0[1],vr1[1],"8320","9344");
      TRRD(vr0[2],vr1[2],"8448","9472"); TRRD(vr0[3],vr1[3],"8576","9600");
      asm volatile("s_waitcnt lgkmcnt(0)" ::: "memory");
      __builtin_amdgcn_sched_barrier(0);
      __builtin_amdgcn_s_setprio(1);
      #pragma unroll
      for (int d4=0;d4<4;d4++){
        #pragma unroll
        for (int i=0;i<4;i++){ uu.us[i]=vr0[d4][i]; uu.us[4+i]=vr1[d4][i]; }
        o[d4] = __builtin_amdgcn_mfma_f32_16x16x32_bf16(pav, uu.v, o[d4], 0,0,0);
      }
      __builtin_amdgcn_s_setprio(0);
      TRRD(vr0[0],vr1[0],"8704","9728"); TRRD(vr0[1],vr1[1],"8832","9856");
      TRRD(vr0[2],vr1[2],"8960","9984"); TRRD(vr0[3],vr1[3],"9088","10112");
      asm volatile("s_waitcnt lgkmcnt(0)" ::: "memory");
      __builtin_amdgcn_sched_barrier(0);
      __builtin_amdgcn_s_setprio(1);
      #pragma unroll
      for (int d4=0;d4<4;d4++){
        #pragma unroll
        for (int i=0;i<4;i++){ uu.us[i]=vr0[d4][i]; uu.us[4+i]=vr1[d4][i]; }
        o[4+d4] = __builtin_amdgcn_mfma_f32_16x16x32_bf16(pav, uu.v, o[4+d4], 0,0,0);
      }
      __builtin_amdgcn_s_setprio(0);
    }
  };

  int buf = 0;
  stage_paged_full(0, 0);
  __syncthreads();
  for (int T=0; T<NT; ++T){
    const bool pre = (T+1 < NT);
    const bool np  = pre && (T+1 < 32);
    if (pre && !np) stage_causal(T+1, buf^1);
    // T14: issue next paged tile's f32 loads BEFORE process (latency hides under compute)
    float4 kr[4], vr_[4];
    if (np){
      const int Tn = T+1;
      const size_t pb  = ((((size_t)(Tn>>2)<<3) + (size_t)b)*16 + (size_t)h) << 15;
      const size_t off = (size_t)(Tn&3)<<13;
      const float* kp = kpf + pb + off;
      const float* vp = vpf + pb + off;
      #pragma unroll
      for (int j=0;j<4;j++) kr[j]  = *reinterpret_cast<const float4*>(kp + ksrc[j]);
      #pragma unroll
      for (int j=0;j<4;j++) vr_[j] = *reinterpret_cast<const float4*>(vp + vsrc[j]);
    }
    int lo=0, hi=64, ktg=0; bool causal=false, masked=false, skip=false;
    if (T < 32){
      const int pg = T>>2, to = T&3;
      const int start = page_pos[(pg*8+b)*2], plen = page_pos[(pg*8+b)*2+1];
      lo = start - (to<<6); hi = start + plen - (to<<6); if (hi>64) hi=64;
      masked = (lo > 0) || (hi < 64);
      skip = (hi <= 0) || (lo >= 64);
    } else {
      const int kt = T-32; ktg = kt<<6;
      hi = len_b - ktg; if (hi>64) hi=64;
      skip = (ktg > q0w + 15) || (hi <= 0);
      causal = (ktg + 63 > q0w);
      masked = causal || (hi < 64);
    }
    if (!skip) process(buf, lo, hi, masked, causal, ktg);
    if (np){
      char* kd = (char*)Ks + ((buf^1)<<14);
      char* vd = (char*)Vs + ((buf^1)<<14);
      #pragma unroll
      for (int j=0;j<4;j++){
        bf16x4 o4; o4[0]=(bf16)kr[j].x; o4[1]=(bf16)kr[j].y; o4[2]=(bf16)kr[j].z; o4[3]=(bf16)kr[j].w;
        *reinterpret_cast<bf16x4*>(kd + ((t + (j<<9))<<3)) = o4;
      }
      #pragma unroll
      for (int j=0;j<4;j++){
        bf16x4 o4; o4[0]=(bf16)vr_[j].x; o4[1]=(bf16)vr_[j].y; o4[2]=(bf16)vr_[j].z; o4[3]=(bf16)vr_[j].w;
        *reinterpret_cast<bf16x4*>(vd + ((t + (j<<9))<<3)) = o4;
      }
    }
    asm volatile("s_waitcnt vmcnt(0)" ::: "memory");
    __syncthreads();
    buf ^= 1;
  }

  {
    float tl = lsum;
    tl += __shfl_xor(tl, 16, 64);
    tl += __shfl_xor(tl, 32, 64);
    const float inv = 1.f / fmaxf(tl, 1e-9f);
    #pragma unroll
    for (int ri=0;ri<4;ri++){
      const float iv = __shfl(inv, (l&48) | ((g<<2)+ri), 64);
      const int q = q0w + (g<<2) + ri;
      #pragma unroll
      for (int dcb=0;dcb<8;dcb++)
        ctx[(((size_t)(b<<10) + q)<<11) + (h<<7) + (dcb<<4) + c] = (bf16)(o[dcb][ri]*iv);
    }
  }
}

// ---------------- launcher ----------------
extern "C" void kernel_launch(void* const* d_in, const int* in_sizes, int n_in,
                              void* d_out, int out_size, void* d_ws, size_t ws_size,
                              hipStream_t stream)
{
  const float* hidden  = (const float*)d_in[0];
  const float* W_attn  = (const float*)d_in[1];
  const float* b_attn  = (const float*)d_in[2];
  const float* W_proj  = (const float*)d_in[3];
  const float* b_proj  = (const float*)d_in[4];
  const float* k_pages = (const float*)d_in[5];
  const float* v_pages = (const float*)d_in[6];
  const int*   page_pos  = (const int*)d_in[7];
  const int*   input_pos = (const int*)d_in[8];
  float* out = (float*)d_out;
  char* ws = (char*)d_ws;
  bf16* A1  = (bf16*)(ws);              // 8192x2048 bf16 (32MB); reused as ctx
  bf16* Wt1 = (bf16*)(ws + 33554432);   // 6144x2048 bf16 (24MB)
  bf16* Wt2 = (bf16*)(ws + 58720256);   // 2048x2048 bf16 (8MB)
  bf16* qb  = (bf16*)(ws + 67108864);   // [8,16,1024,128] bf16 (32MB)
  bf16* kb  = (bf16*)(ws + 100663296);
  bf16* vb  = (bf16*)(ws + 134217728);  // end 167,772,160
  bf16* ctx = A1;

  k_cvt_bf16<<<16384, 256, 0, stream>>>(hidden, A1, 4194304);
  k_transpose_cvt<<<dim3(192,64), 256, 0, stream>>>(W_attn, Wt1, 2048, 6144);
  k_transpose_cvt<<<dim3(64,64),  256, 0, stream>>>(W_proj, Wt2, 2048, 2048);
  k_gemm8<0><<<768, 512, 0, stream>>>(A1, Wt1, b_attn, 6144, 2048, qb, kb, vb, nullptr);
  k_attn<<<1024, 512, 0, stream>>>(qb, kb, vb, k_pages, v_pages, page_pos, input_pos, ctx);
  k_gemm8<1><<<256, 512, 0, stream>>>(ctx, Wt2, b_proj, 2048, 2048, nullptr, nullptr, nullptr, out);
}

// Round 17
// 712.311 us; speedup vs baseline: 1.6438x; 1.6438x over previous
//
#include <hip/hip_runtime.h>

typedef __bf16 bf16;
typedef __bf16 bf16x8 __attribute__((ext_vector_type(8)));
typedef __bf16 bf16x4 __attribute__((ext_vector_type(4)));
typedef float f32x4 __attribute__((ext_vector_type(4)));
typedef unsigned short u16x4 __attribute__((ext_vector_type(4)));
typedef __attribute__((address_space(3))) const void as3_void;
typedef __attribute__((address_space(3))) const char as3_char;

#define GLOAD16(G,L) __builtin_amdgcn_global_load_lds((__attribute__((address_space(1))) const void*)(G), (__attribute__((address_space(3))) void*)(L), 16, 0, 0)

// ---------------- conversion kernels ----------------
__global__ void k_cvt_bf16(const float* __restrict__ src, bf16* __restrict__ dst, int n4){
  int i = blockIdx.x*256 + threadIdx.x;
  if (i < n4){
    float4 v = reinterpret_cast<const float4*>(src)[i];
    bf16x4 o; o[0]=(bf16)v.x; o[1]=(bf16)v.y; o[2]=(bf16)v.z; o[3]=(bf16)v.w;
    reinterpret_cast<bf16x4*>(dst)[i] = o;
  }
}

// src: K x N (f32) -> dst: N x K (bf16)
__global__ void k_transpose_cvt(const float* __restrict__ src, bf16* __restrict__ dst, int K, int N){
  __shared__ float tile[32][33];
  int n0 = blockIdx.x*32, k0 = blockIdx.y*32;
  int tx = threadIdx.x & 31, ty = threadIdx.x >> 5; // 32 x 8
  #pragma unroll
  for (int i=0;i<32;i+=8)
    tile[ty+i][tx] = src[(size_t)(k0+ty+i)*N + n0+tx];
  __syncthreads();
  #pragma unroll
  for (int i=0;i<32;i+=8)
    dst[(size_t)(n0+ty+i)*K + k0+tx] = (bf16)tile[tx][ty+i];
}

// ---------------- 256x256 bf16 MFMA GEMM, 8 waves, BK=64, 4-phase K-tile schedule ----------------
// Blocks with swz >= nTiles run a grid-stride f32->bf16 page conversion instead (fused
// with EPI==0 so the 128us page-cvt hides under the MFMA-bound GEMM; cvt blocks are
// bid%8 in {6,7} -> start immediately, spread across XCDs' dispatch order).
template<int EPI>
__global__ __launch_bounds__(512,2) void k_gemm8(
    const bf16* __restrict__ A, const bf16* __restrict__ Bt,
    const float* __restrict__ bias, int N, int K,
    bf16* __restrict__ q_out, bf16* __restrict__ k_out, bf16* __restrict__ v_out,
    float* __restrict__ c_out,
    const float* __restrict__ kpf, const float* __restrict__ vpf,
    bf16* __restrict__ kpb, bf16* __restrict__ vpb, int nTiles)
{
  __shared__ bf16 S[2][4][8192];   // [buf][A0,A1,B0,B1][128*64]
  const int t = threadIdx.x, w = t>>6, l = t&63, g = l>>4, c = l&15;
  const int wm = w>>2, wn = w&3;   // 2M x 4N waves
  const int nb = N>>8;
  const int cpx = gridDim.x>>3;
  const int swz = (blockIdx.x&7)*cpx + (blockIdx.x>>3);   // XCD swizzle (grid%8==0)
  if (swz >= nTiles){
    // ---- fused page conversion: 8.39M float4 each for K and V ----
    const int ci = swz - nTiles;               // 0..255
    const int stride = (gridDim.x - nTiles)*512;
    const float4* ks = (const float4*)kpf;
    const float4* vs = (const float4*)vpf;
    bf16x4* kd = (bf16x4*)kpb;
    bf16x4* vd = (bf16x4*)vpb;
    for (int i = ci*512 + t; i < 8388608; i += stride){
      float4 v = ks[i];
      bf16x4 o4; o4[0]=(bf16)v.x; o4[1]=(bf16)v.y; o4[2]=(bf16)v.z; o4[3]=(bf16)v.w;
      kd[i] = o4;
    }
    for (int i = ci*512 + t; i < 8388608; i += stride){
      float4 v = vs[i];
      bf16x4 o4; o4[0]=(bf16)v.x; o4[1]=(bf16)v.y; o4[2]=(bf16)v.z; o4[3]=(bf16)v.w;
      vd[i] = o4;
    }
    return;
  }
  const int m0 = (swz/nb)<<8, n0 = (swz%nb)<<8;
  const int NK = K>>6;

  int abase[2];
  #pragma unroll
  for (int kk=0; kk<2; ++kk)
    abase[kk] = (c<<7) + (((((kk<<2)|g)) ^ (c&7))<<4);

  const int r0 = t>>3;
  const int col0 = ((t&7) ^ (r0&7))<<3;

  auto stageA = [&](int kt2){
    #pragma unroll
    for (int hh=0; hh<2; ++hh){
      const bf16* sp = A + (size_t)(m0 + hh*128)*K + (kt2<<6);
      char* dp = (char*)&S[kt2&1][hh][0];
      GLOAD16(sp + (size_t)r0*K + col0,      dp + t*16);
      GLOAD16(sp + (size_t)(r0+64)*K + col0, dp + (t+512)*16);
    }
  };
  auto stageB = [&](int kt2){
    #pragma unroll
    for (int hh=0; hh<2; ++hh){
      const bf16* sp = Bt + (size_t)(n0 + hh*128)*K + (kt2<<6);
      char* dp = (char*)&S[kt2&1][2+hh][0];
      GLOAD16(sp + (size_t)r0*K + col0,      dp + t*16);
      GLOAD16(sp + (size_t)(r0+64)*K + col0, dp + (t+512)*16);
    }
  };

  f32x4 acc[8][4] = {};

  stageA(0); stageB(0);
  asm volatile("s_waitcnt vmcnt(0)" ::: "memory");
  __builtin_amdgcn_s_barrier();

  for (int kt=0; kt<NK; ++kt){
    const int bufc = kt&1;
    const char* Ab_ = (const char*)&S[bufc][wm][0];
    const char* Bb_ = (const char*)&S[bufc][2+(wn>>1)][0] + ((wn&1)<<13);
    const bool pre = (kt+1 < NK);
    bf16x8 af[4][2], bfr[2][2];

    auto lda = [&](int mh){
      #pragma unroll
      for (int mf=0; mf<4; ++mf)
        #pragma unroll
        for (int kk=0; kk<2; ++kk)
          af[mf][kk] = *reinterpret_cast<const bf16x8*>(Ab_ + abase[kk] + mh*8192 + mf*2048);
    };
    auto ldb = [&](int nh){
      #pragma unroll
      for (int nf=0; nf<2; ++nf)
        #pragma unroll
        for (int kk=0; kk<2; ++kk)
          bfr[nf][kk] = *reinterpret_cast<const bf16x8*>(Bb_ + abase[kk] + nh*4096 + nf*2048);
    };
    auto cluster = [&](int mh, int nh){
      __builtin_amdgcn_s_barrier();
      asm volatile("s_waitcnt lgkmcnt(0)" ::: "memory");
      __builtin_amdgcn_sched_barrier(0);
      __builtin_amdgcn_s_setprio(1);
      #pragma unroll
      for (int mf=0; mf<4; ++mf)
        #pragma unroll
        for (int nf=0; nf<2; ++nf)
          #pragma unroll
          for (int kk=0; kk<2; ++kk)
            acc[mh*4+mf][nh*2+nf] =
              __builtin_amdgcn_mfma_f32_16x16x32_bf16(af[mf][kk], bfr[nf][kk], acc[mh*4+mf][nh*2+nf], 0,0,0);
      __builtin_amdgcn_s_setprio(0);
    };

    lda(0); ldb(0);
    if (pre) stageA(kt+1);
    cluster(0,0);
    __builtin_amdgcn_s_barrier();
    ldb(1);
    if (pre) stageB(kt+1);
    cluster(0,1);
    __builtin_amdgcn_s_barrier();
    lda(1);
    cluster(1,1);
    __builtin_amdgcn_s_barrier();
    ldb(0);
    cluster(1,0);
    asm volatile("s_waitcnt vmcnt(0)" ::: "memory");
    __builtin_amdgcn_s_barrier();
  }

  if constexpr (EPI==0){
    #pragma unroll
    for (int NF=0; NF<4; ++NF){
      const int col = n0 + wn*64 + NF*16 + c;
      const int sec = col>>11; const int rem = col&2047;
      const int hhd = rem>>7;  const int dd = rem&127;
      bf16* dst = (sec==0) ? q_out : ((sec==1) ? k_out : v_out);
      const float bv = bias[col];
      const float qs = (sec==0) ? 0.12751743f : 1.0f;  // pre-scale Q: 1/sqrt(128)*log2(e)
      #pragma unroll
      for (int MF=0; MF<8; ++MF)
        #pragma unroll
        for (int ri=0; ri<4; ++ri){
          const int row = m0 + wm*128 + MF*16 + (g<<2) + ri;
          const int bb = row>>10, qp = row&1023;
          dst[(((size_t)(bb*16+hhd)*1024 + qp)<<7) + dd] = (bf16)((acc[MF][NF][ri] + bv)*qs);
        }
    }
  } else {
    #pragma unroll
    for (int NF=0; NF<4; ++NF){
      const int col = n0 + wn*64 + NF*16 + c;
      const float bv = bias[col];
      #pragma unroll
      for (int MF=0; MF<8; ++MF)
        #pragma unroll
        for (int ri=0; ri<4; ++ri){
          const int row = m0 + wm*128 + MF*16 + (g<<2) + ri;
          c_out[(size_t)row*N + col] = acc[MF][NF][ri] + bv;
        }
    }
  }
}

// 2 x ds_read_b64_tr_b16 with literal offsets from the single per-tile V base (vbL, LDS addr-space)
#define TRRD(R0, R1, O0, O1) \
  asm volatile("ds_read_b64_tr_b16 %0, %2 offset:" O0 "\n\t" \
               "ds_read_b64_tr_b16 %1, %2 offset:" O1 \
               : "=&v"(R0), "=&v"(R1) : "v"(vbL) : "memory")

// ---------------- fused paged + causal flash attention (r14 version, 290us known-good) ----------------
__global__ __launch_bounds__(512) __attribute__((amdgpu_waves_per_eu(4,4))) void k_attn(
    const bf16* __restrict__ qb, const bf16* __restrict__ kb, const bf16* __restrict__ vb,
    const bf16* __restrict__ kpb, const bf16* __restrict__ vpb,
    const int* __restrict__ page_pos, const int* __restrict__ input_pos,
    bf16* __restrict__ ctx)
{
  __shared__ bf16 Ks[2*64*128];
  __shared__ bf16 Vs[2*64*128];
  const int t = threadIdx.x, w = t>>6, l = t&63, g = l>>4, c = l&15;
  const int bid = blockIdx.x;
  const int wg = (bid&7)*128 + (bid>>3);
  const int qt = wg & 7, h = (wg>>3)&15, b = wg>>7;
  const int q0w = (qt<<7) + (w<<4);
  const size_t bh = (size_t)(b*16 + h);

  const bf16* qptr = qb + (bh<<17);
  bf16x8 qf[4];
  #pragma unroll
  for (int kc=0;kc<4;kc++)
    qf[kc] = *reinterpret_cast<const bf16x8*>(qptr + ((size_t)(q0w + c)<<7) + kc*32 + (g<<3));

  int kbase[4];
  #pragma unroll
  for (int kc=0;kc<4;kc++)
    kbase[kc] = (c<<8) + ((((kc<<2)|g) ^ c)<<4);
  const int voffL = (g<<11) + (c<<3);   // V tr_read base offset

  int kOff[2], vOff[2];
  #pragma unroll
  for (int j=0;j<2;j++){
    const int slot = t + (j<<9);
    {
      const int a = slot<<4; const int r = a>>8; const int co = (a&255) ^ ((r&15)<<4);
      kOff[j] = (r<<7) + (co>>1);
    }
    {
      const int s_ = slot;
      const int p  = ((s_>>6)<<2) | ((s_>>1)&3);
      const int d0 = (((s_>>3)&7)<<4) | ((s_&1)<<3);
      const int pp = (p&32) | ((p&4)<<2) | (((p>>3)&3)<<2) | (p&3); // pi(p)
      vOff[j] = (pp<<7) + d0;
    }
  }
  const bf16* kcb = kb + (bh<<17);
  const bf16* vcb = vb + (bh<<17);
  const int len_b = input_pos[b*2+1];
  const int NT = 32 + ((qt+1)<<1);

  f32x4 o[8] = {};
  float mrow = -1e38f;
  float lsum = 0.f;

  auto tsrc = [&](int T, const bf16*& ks, const bf16*& vs_){
    if (T < 32){
      size_t pb = ((((size_t)(T>>2)<<3) + (size_t)b)*16 + (size_t)h) << 15;
      size_t off = (size_t)(T&3)<<13;
      ks = kpb + pb + off; vs_ = vpb + pb + off;
    } else {
      int kt = T-32; ks = kcb + ((size_t)kt<<13); vs_ = vcb + ((size_t)kt<<13);
    }
  };
  auto stage = [&](int T, int buf){
    const bf16 *ks, *vs_; tsrc(T, ks, vs_);
    char* kd = (char*)Ks + (buf<<14) + (w<<10);
    char* vd = (char*)Vs + (buf<<14) + (w<<10);
    #pragma unroll
    for (int j=0;j<2;j++){
      GLOAD16(ks  + kOff[j], kd + (j<<13));
      GLOAD16(vs_ + vOff[j], vd + (j<<13));
    }
  };

  auto process = [&](int buf, int lo, int hi, bool masked, bool causal, int ktg){
    const char* Kb = (const char*)Ks + (buf<<14);
    as3_char* vbL = (as3_char*)((as3_char*)Vs + (buf<<14) + voffL);
    f32x4 s[4] = {};
    #pragma unroll
    for (int kc=0;kc<4;kc++){
      const char* bk = Kb + kbase[kc];
      bf16x8 kf[4];
      #pragma unroll
      for (int cb=0;cb<4;cb++)
        kf[cb] = *reinterpret_cast<const bf16x8*>(bk + (cb<<12));
      __builtin_amdgcn_s_setprio(1);
      #pragma unroll
      for (int cb=0;cb<4;cb++)
        s[cb] = __builtin_amdgcn_mfma_f32_16x16x32_bf16(kf[cb], qf[kc], s[cb], 0,0,0);
      __builtin_amdgcn_s_setprio(0);
    }
    if (masked){
      #pragma unroll
      for (int cb=0;cb<4;cb++)
        #pragma unroll
        for (int ri=0;ri<4;ri++){
          const int kvl = (cb<<4) + (g<<2) + ri;
          bool ok = (kvl >= lo) && (kvl < hi);
          if (causal) ok = ok && ((ktg + kvl) <= (q0w + c));
          s[cb][ri] = ok ? s[cb][ri] : -3e38f;
        }
    }
    {
      float m0_ = fmaxf(fmaxf(s[0][0], s[0][1]), fmaxf(s[0][2], s[0][3]));
      float m1_ = fmaxf(fmaxf(s[1][0], s[1][1]), fmaxf(s[1][2], s[1][3]));
      float m2_ = fmaxf(fmaxf(s[2][0], s[2][1]), fmaxf(s[2][2], s[2][3]));
      float m3_ = fmaxf(fmaxf(s[3][0], s[3][1]), fmaxf(s[3][2], s[3][3]));
      float mx = fmaxf(fmaxf(m0_, m1_), fmaxf(m2_, m3_));
      const int defer = __all(mx - mrow <= 11.5f);
      if (!defer){
        float mr = fmaxf(mx, __shfl_xor(mx, 16, 64));
        mr = fmaxf(mr, __shfl_xor(mr, 32, 64));
        const float mn = fmaxf(mrow, mr);
        const float al = exp2f(mrow - mn);
        mrow = mn;
        lsum *= al;
        #pragma unroll
        for (int ri=0;ri<4;ri++){
          const float av = __shfl(al, (l&48) | ((g<<2)+ri), 64);
          #pragma unroll
          for (int dcb=0;dcb<8;dcb++) o[dcb][ri] *= av;
        }
      }
      float ps = 0.f;
      #pragma unroll
      for (int cb=0;cb<4;cb++)
        #pragma unroll
        for (int ri=0;ri<4;ri++){
          const float e = exp2f(s[cb][ri] - mrow);
          s[cb][ri] = e; ps += e;
        }
      lsum += ps;
    }
    {
      u16x4 vr0[4], vr1[4];
      bf16x8 pav;
      union { unsigned short us[8]; bf16x8 v; } uu;
      #pragma unroll
      for (int e=0;e<8;e++) pav[e] = (bf16)s[e>>2][e&3];
      TRRD(vr0[0],vr1[0],"0","1024");  TRRD(vr0[1],vr1[1],"128","1152");
      TRRD(vr0[2],vr1[2],"256","1280");TRRD(vr0[3],vr1[3],"384","1408");
      asm volatile("s_waitcnt lgkmcnt(0)" ::: "memory");
      __builtin_amdgcn_sched_barrier(0);
      __builtin_amdgcn_s_setprio(1);
      #pragma unroll
      for (int d4=0;d4<4;d4++){
        #pragma unroll
        for (int i=0;i<4;i++){ uu.us[i]=vr0[d4][i]; uu.us[4+i]=vr1[d4][i]; }
        o[d4] = __builtin_amdgcn_mfma_f32_16x16x32_bf16(pav, uu.v, o[d4], 0,0,0);
      }
      __builtin_amdgcn_s_setprio(0);
      TRRD(vr0[0],vr1[0],"512","1536");  TRRD(vr0[1],vr1[1],"640","1664");
      TRRD(vr0[2],vr1[2],"768","1792");  TRRD(vr0[3],vr1[3],"896","1920");
      asm volatile("s_waitcnt lgkmcnt(0)" ::: "memory");
      __builtin_amdgcn_sched_barrier(0);
      __builtin_amdgcn_s_setprio(1);
      #pragma unroll
      for (int d4=0;d4<4;d4++){
        #pragma unroll
        for (int i=0;i<4;i++){ uu.us[i]=vr0[d4][i]; uu.us[4+i]=vr1[d4][i]; }
        o[4+d4] = __builtin_amdgcn_mfma_f32_16x16x32_bf16(pav, uu.v, o[4+d4], 0,0,0);
      }
      __builtin_amdgcn_s_setprio(0);
      #pragma unroll
      for (int e=0;e<8;e++) pav[e] = (bf16)s[2+(e>>2)][e&3];
      TRRD(vr0[0],vr1[0],"8192","9216"); TRRD(vr0[1],vr1[1],"8320","9344");
      TRRD(vr0[2],vr1[2],"8448","9472"); TRRD(vr0[3],vr1[3],"8576","9600");
      asm volatile("s_waitcnt lgkmcnt(0)" ::: "memory");
      __builtin_amdgcn_sched_barrier(0);
      __builtin_amdgcn_s_setprio(1);
      #pragma unroll
      for (int d4=0;d4<4;d4++){
        #pragma unroll
        for (int i=0;i<4;i++){ uu.us[i]=vr0[d4][i]; uu.us[4+i]=vr1[d4][i]; }
        o[d4] = __builtin_amdgcn_mfma_f32_16x16x32_bf16(pav, uu.v, o[d4], 0,0,0);
      }
      __builtin_amdgcn_s_setprio(0);
      TRRD(vr0[0],vr1[0],"8704","9728"); TRRD(vr0[1],vr1[1],"8832","9856");
      TRRD(vr0[2],vr1[2],"8960","9984"); TRRD(vr0[3],vr1[3],"9088","10112");
      asm volatile("s_waitcnt lgkmcnt(0)" ::: "memory");
      __builtin_amdgcn_sched_barrier(0);
      __builtin_amdgcn_s_setprio(1);
      #pragma unroll
      for (int d4=0;d4<4;d4++){
        #pragma unroll
        for (int i=0;i<4;i++){ uu.us[i]=vr0[d4][i]; uu.us[4+i]=vr1[d4][i]; }
        o[4+d4] = __builtin_amdgcn_mfma_f32_16x16x32_bf16(pav, uu.v, o[4+d4], 0,0,0);
      }
      __builtin_amdgcn_s_setprio(0);
    }
  };

  int buf = 0;
  stage(0, 0);
  asm volatile("s_waitcnt vmcnt(0)" ::: "memory");
  __syncthreads();
  for (int T=0; T<NT; ++T){
    if (T+1 < NT) stage(T+1, buf^1);
    int lo=0, hi=64, ktg=0; bool causal=false, masked=false, skip=false;
    if (T < 32){
      const int pg = T>>2, to = T&3;
      const int start = page_pos[(pg*8+b)*2], plen = page_pos[(pg*8+b)*2+1];
      lo = start - (to<<6); hi = start + plen - (to<<6); if (hi>64) hi=64;
      masked = (lo > 0) || (hi < 64);
      skip = (hi <= 0) || (lo >= 64);
    } else {
      const int kt = T-32; ktg = kt<<6;
      hi = len_b - ktg; if (hi>64) hi=64;
      skip = (ktg > q0w + 15) || (hi <= 0);
      causal = (ktg + 63 > q0w);
      masked = causal || (hi < 64);
    }
    if (!skip) process(buf, lo, hi, masked, causal, ktg);
    asm volatile("s_waitcnt vmcnt(0)" ::: "memory");
    __syncthreads();
    buf ^= 1;
  }

  {
    float tl = lsum;
    tl += __shfl_xor(tl, 16, 64);
    tl += __shfl_xor(tl, 32, 64);
    const float inv = 1.f / fmaxf(tl, 1e-9f);
    #pragma unroll
    for (int ri=0;ri<4;ri++){
      const float iv = __shfl(inv, (l&48) | ((g<<2)+ri), 64);
      const int q = q0w + (g<<2) + ri;
      #pragma unroll
      for (int dcb=0;dcb<8;dcb++)
        ctx[(((size_t)(b<<10) + q)<<11) + (h<<7) + (dcb<<4) + c] = (bf16)(o[dcb][ri]*iv);
    }
  }
}

// ---------------- launcher ----------------
extern "C" void kernel_launch(void* const* d_in, const int* in_sizes, int n_in,
                              void* d_out, int out_size, void* d_ws, size_t ws_size,
                              hipStream_t stream)
{
  const float* hidden  = (const float*)d_in[0];
  const float* W_attn  = (const float*)d_in[1];
  const float* b_attn  = (const float*)d_in[2];
  const float* W_proj  = (const float*)d_in[3];
  const float* b_proj  = (const float*)d_in[4];
  const float* k_pages = (const float*)d_in[5];
  const float* v_pages = (const float*)d_in[6];
  const int*   page_pos  = (const int*)d_in[7];
  const int*   input_pos = (const int*)d_in[8];
  float* out = (float*)d_out;
  char* ws = (char*)d_ws;
  bf16* A1  = (bf16*)(ws);              // 8192x2048 bf16 (32MB); reused as ctx
  bf16* Wt1 = (bf16*)(ws + 33554432);   // 6144x2048 bf16 (24MB)
  bf16* Wt2 = (bf16*)(ws + 58720256);   // 2048x2048 bf16 (8MB)
  bf16* qb  = (bf16*)(ws + 67108864);   // [8,16,1024,128] bf16 (32MB)
  bf16* kb  = (bf16*)(ws + 100663296);
  bf16* vb  = (bf16*)(ws + 134217728);
  bf16* kpb = (bf16*)(ws + 167772160);  // bf16 pages (64MB)
  bf16* vpb = (bf16*)(ws + 234881024);  // bf16 pages (64MB); end 301,989,888
  bf16* ctx = A1;

  k_cvt_bf16<<<16384, 256, 0, stream>>>(hidden, A1, 4194304);
  k_transpose_cvt<<<dim3(192,64), 256, 0, stream>>>(W_attn, Wt1, 2048, 6144);
  k_transpose_cvt<<<dim3(64,64),  256, 0, stream>>>(W_proj, Wt2, 2048, 2048);
  // 768 GEMM tiles + 256 fused page-cvt blocks
  k_gemm8<0><<<1024, 512, 0, stream>>>(A1, Wt1, b_attn, 6144, 2048, qb, kb, vb, nullptr,
                                       k_pages, v_pages, kpb, vpb, 768);
  k_attn<<<1024, 512, 0, stream>>>(qb, kb, vb, kpb, vpb, page_pos, input_pos, ctx);
  k_gemm8<1><<<256, 512, 0, stream>>>(ctx, Wt2, b_proj, 2048, 2048, nullptr, nullptr, nullptr, out,
                                      nullptr, nullptr, nullptr, nullptr, 256);
}

// Round 18
// 630.348 us; speedup vs baseline: 1.8575x; 1.1300x over previous
//
#include <hip/hip_runtime.h>

typedef __bf16 bf16;
typedef __bf16 bf16x8 __attribute__((ext_vector_type(8)));
typedef __bf16 bf16x4 __attribute__((ext_vector_type(4)));
typedef float f32x4 __attribute__((ext_vector_type(4)));
typedef unsigned short u16x4 __attribute__((ext_vector_type(4)));
typedef __attribute__((address_space(3))) const void as3_void;
typedef __attribute__((address_space(3))) const char as3_char;

#define GLOAD16(G,L) __builtin_amdgcn_global_load_lds((__attribute__((address_space(1))) const void*)(G), (__attribute__((address_space(3))) void*)(L), 16, 0, 0)

// ---------------- conversion kernels ----------------
__global__ void k_cvt_bf16(const float* __restrict__ src, bf16* __restrict__ dst, int n4){
  int i = blockIdx.x*256 + threadIdx.x;
  if (i < n4){
    float4 v = reinterpret_cast<const float4*>(src)[i];
    bf16x4 o; o[0]=(bf16)v.x; o[1]=(bf16)v.y; o[2]=(bf16)v.z; o[3]=(bf16)v.w;
    reinterpret_cast<bf16x4*>(dst)[i] = o;
  }
}

// merged transpose: bx<192 -> W_attn (K=2048 x N=6144), else W_proj (K=2048 x N=2048)
__global__ void k_transpose_cvt2(const float* __restrict__ srcA, bf16* __restrict__ dstA,
                                 const float* __restrict__ srcB, bf16* __restrict__ dstB){
  __shared__ float tile[32][33];
  const int K = 2048;
  const bool isA = (blockIdx.x < 192);
  const float* src = isA ? srcA : srcB;
  bf16* dst = isA ? dstA : dstB;
  const int N = isA ? 6144 : 2048;
  int n0 = (isA ? blockIdx.x : (blockIdx.x - 192))*32, k0 = blockIdx.y*32;
  int tx = threadIdx.x & 31, ty = threadIdx.x >> 5; // 32 x 8
  #pragma unroll
  for (int i=0;i<32;i+=8)
    tile[ty+i][tx] = src[(size_t)(k0+ty+i)*N + n0+tx];
  __syncthreads();
  #pragma unroll
  for (int i=0;i<32;i+=8)
    dst[(size_t)(n0+ty+i)*K + k0+tx] = (bf16)tile[tx][ty+i];
}

// ---------------- 256x256 bf16 MFMA GEMM, 8 waves, BK=64, 4-phase K-tile schedule ----------------
template<int EPI>
__global__ __launch_bounds__(512,2) void k_gemm8(
    const bf16* __restrict__ A, const bf16* __restrict__ Bt,
    const float* __restrict__ bias, int N, int K,
    bf16* __restrict__ q_out, bf16* __restrict__ k_out, bf16* __restrict__ v_out,
    float* __restrict__ c_out)
{
  __shared__ bf16 S[2][4][8192];   // [buf][A0,A1,B0,B1][128*64]
  const int t = threadIdx.x, w = t>>6, l = t&63, g = l>>4, c = l&15;
  const int wm = w>>2, wn = w&3;   // 2M x 4N waves
  const int nb = N>>8;
  const int cpx = gridDim.x>>3;
  const int swz = (blockIdx.x&7)*cpx + (blockIdx.x>>3);   // XCD swizzle (grid%8==0)
  const int m0 = (swz/nb)<<8, n0 = (swz%nb)<<8;
  const int NK = K>>6;

  int abase[2];
  #pragma unroll
  for (int kk=0; kk<2; ++kk)
    abase[kk] = (c<<7) + (((((kk<<2)|g)) ^ (c&7))<<4);

  const int r0 = t>>3;
  const int col0 = ((t&7) ^ (r0&7))<<3;

  auto stageA = [&](int kt2){
    #pragma unroll
    for (int hh=0; hh<2; ++hh){
      const bf16* sp = A + (size_t)(m0 + hh*128)*K + (kt2<<6);
      char* dp = (char*)&S[kt2&1][hh][0];
      GLOAD16(sp + (size_t)r0*K + col0,      dp + t*16);
      GLOAD16(sp + (size_t)(r0+64)*K + col0, dp + (t+512)*16);
    }
  };
  auto stageB = [&](int kt2){
    #pragma unroll
    for (int hh=0; hh<2; ++hh){
      const bf16* sp = Bt + (size_t)(n0 + hh*128)*K + (kt2<<6);
      char* dp = (char*)&S[kt2&1][2+hh][0];
      GLOAD16(sp + (size_t)r0*K + col0,      dp + t*16);
      GLOAD16(sp + (size_t)(r0+64)*K + col0, dp + (t+512)*16);
    }
  };

  f32x4 acc[8][4] = {};

  stageA(0); stageB(0);
  asm volatile("s_waitcnt vmcnt(0)" ::: "memory");
  __builtin_amdgcn_s_barrier();

  for (int kt=0; kt<NK; ++kt){
    const int bufc = kt&1;
    const char* Ab_ = (const char*)&S[bufc][wm][0];
    const char* Bb_ = (const char*)&S[bufc][2+(wn>>1)][0] + ((wn&1)<<13);
    const bool pre = (kt+1 < NK);
    bf16x8 af[4][2], bfr[2][2];

    auto lda = [&](int mh){
      #pragma unroll
      for (int mf=0; mf<4; ++mf)
        #pragma unroll
        for (int kk=0; kk<2; ++kk)
          af[mf][kk] = *reinterpret_cast<const bf16x8*>(Ab_ + abase[kk] + mh*8192 + mf*2048);
    };
    auto ldb = [&](int nh){
      #pragma unroll
      for (int nf=0; nf<2; ++nf)
        #pragma unroll
        for (int kk=0; kk<2; ++kk)
          bfr[nf][kk] = *reinterpret_cast<const bf16x8*>(Bb_ + abase[kk] + nh*4096 + nf*2048);
    };
    auto cluster = [&](int mh, int nh){
      __builtin_amdgcn_s_barrier();
      asm volatile("s_waitcnt lgkmcnt(0)" ::: "memory");
      __builtin_amdgcn_sched_barrier(0);
      __builtin_amdgcn_s_setprio(1);
      #pragma unroll
      for (int mf=0; mf<4; ++mf)
        #pragma unroll
        for (int nf=0; nf<2; ++nf)
          #pragma unroll
          for (int kk=0; kk<2; ++kk)
            acc[mh*4+mf][nh*2+nf] =
              __builtin_amdgcn_mfma_f32_16x16x32_bf16(af[mf][kk], bfr[nf][kk], acc[mh*4+mf][nh*2+nf], 0,0,0);
      __builtin_amdgcn_s_setprio(0);
    };

    lda(0); ldb(0);
    if (pre) stageA(kt+1);
    cluster(0,0);
    __builtin_amdgcn_s_barrier();
    ldb(1);
    if (pre) stageB(kt+1);
    cluster(0,1);
    __builtin_amdgcn_s_barrier();
    lda(1);
    cluster(1,1);
    __builtin_amdgcn_s_barrier();
    ldb(0);
    cluster(1,0);
    asm volatile("s_waitcnt vmcnt(0)" ::: "memory");
    __builtin_amdgcn_s_barrier();
  }

  if constexpr (EPI==0){
    #pragma unroll
    for (int NF=0; NF<4; ++NF){
      const int col = n0 + wn*64 + NF*16 + c;
      const int sec = col>>11; const int rem = col&2047;
      const int hhd = rem>>7;  const int dd = rem&127;
      bf16* dst = (sec==0) ? q_out : ((sec==1) ? k_out : v_out);
      const float bv = bias[col];
      const float qs = (sec==0) ? 0.12751743f : 1.0f;  // pre-scale Q: 1/sqrt(128)*log2(e)
      #pragma unroll
      for (int MF=0; MF<8; ++MF)
        #pragma unroll
        for (int ri=0; ri<4; ++ri){
          const int row = m0 + wm*128 + MF*16 + (g<<2) + ri;
          const int bb = row>>10, qp = row&1023;
          dst[(((size_t)(bb*16+hhd)*1024 + qp)<<7) + dd] = (bf16)((acc[MF][NF][ri] + bv)*qs);
        }
    }
  } else {
    #pragma unroll
    for (int NF=0; NF<4; ++NF){
      const int col = n0 + wn*64 + NF*16 + c;
      const float bv = bias[col];
      #pragma unroll
      for (int MF=0; MF<8; ++MF)
        #pragma unroll
        for (int ri=0; ri<4; ++ri){
          const int row = m0 + wm*128 + MF*16 + (g<<2) + ri;
          c_out[(size_t)row*N + col] = acc[MF][NF][ri] + bv;
        }
    }
  }
}

// 2 x ds_read_b64_tr_b16 with literal offsets from the single per-tile V base (vbL, LDS addr-space)
#define TRRD(R0, R1, O0, O1) \
  asm volatile("ds_read_b64_tr_b16 %0, %2 offset:" O0 "\n\t" \
               "ds_read_b64_tr_b16 %1, %2 offset:" O1 \
               : "=&v"(R0), "=&v"(R1) : "v"(vbL) : "memory")

// ---------------- fused paged + causal flash attention (r15 version, 350us known-good) ----------------
// Paged tiles staged directly from f32 pages (float4 -> cvt -> ds_write after process);
// causal tiles via global_load_lds bf16. XCD swizzle keeps qt-siblings on one XCD for L2 reuse.
__global__ __launch_bounds__(512) __attribute__((amdgpu_waves_per_eu(4,4))) void k_attn(
    const bf16* __restrict__ qb, const bf16* __restrict__ kb, const bf16* __restrict__ vb,
    const float* __restrict__ kpf, const float* __restrict__ vpf,
    const int* __restrict__ page_pos, const int* __restrict__ input_pos,
    bf16* __restrict__ ctx)
{
  __shared__ bf16 Ks[2*64*128];
  __shared__ bf16 Vs[2*64*128];
  const int t = threadIdx.x, w = t>>6, l = t&63, g = l>>4, c = l&15;
  const int bid = blockIdx.x;
  const int wg = (bid&7)*128 + (bid>>3);
  const int qt = wg & 7, h = (wg>>3)&15, b = wg>>7;
  const int q0w = (qt<<7) + (w<<4);
  const size_t bh = (size_t)(b*16 + h);

  const bf16* qptr = qb + (bh<<17);
  bf16x8 qf[4];
  #pragma unroll
  for (int kc=0;kc<4;kc++)
    qf[kc] = *reinterpret_cast<const bf16x8*>(qptr + ((size_t)(q0w + c)<<7) + kc*32 + (g<<3));

  int kbase[4];
  #pragma unroll
  for (int kc=0;kc<4;kc++)
    kbase[kc] = (c<<8) + ((((kc<<2)|g) ^ c)<<4);
  const int voffL = (g<<11) + (c<<3);   // V tr_read base offset

  // causal staging (gload_lds, 16B slots, 2/thread)
  int kOff[2], vOff[2];
  #pragma unroll
  for (int j=0;j<2;j++){
    const int slot = t + (j<<9);
    {
      const int a = slot<<4; const int r = a>>8; const int co = (a&255) ^ ((r&15)<<4);
      kOff[j] = (r<<7) + (co>>1);
    }
    {
      const int s_ = slot;
      const int p  = ((s_>>6)<<2) | ((s_>>1)&3);
      const int d0 = (((s_>>3)&7)<<4) | ((s_&1)<<3);
      const int pp = (p&32) | ((p&4)<<2) | (((p>>3)&3)<<2) | (p&3); // pi(p)
      vOff[j] = (pp<<7) + d0;
    }
  }
  // paged reg-staging (f32 source, 8B dest units, 4/thread): same maps at half granularity
  int ksrc[4], vsrc[4];
  #pragma unroll
  for (int j=0;j<4;j++){
    const int uu = t + (j<<9);        // 8B dest unit, dest byte = uu*8
    const int s_ = uu>>1, hh = uu&1;
    {
      const int a = s_<<4; const int r = a>>8; const int co = (a&255) ^ ((r&15)<<4);
      ksrc[j] = (r<<7) + (co>>1) + (hh<<2);
    }
    {
      const int p  = ((s_>>6)<<2) | ((s_>>1)&3);
      const int d0 = (((s_>>3)&7)<<4) | ((s_&1)<<3);
      const int pp = (p&32) | ((p&4)<<2) | (((p>>3)&3)<<2) | (p&3);
      vsrc[j] = (pp<<7) + d0 + (hh<<2);
    }
  }
  const bf16* kcb = kb + (bh<<17);
  const bf16* vcb = vb + (bh<<17);
  const int len_b = input_pos[b*2+1];
  const int NT = 32 + ((qt+1)<<1);

  f32x4 o[8] = {};
  float mrow = -1e38f;
  float lsum = 0.f;

  auto stage_causal = [&](int T, int buf){
    const int kt = T-32;
    const bf16* ks  = kcb + ((size_t)kt<<13);
    const bf16* vs_ = vcb + ((size_t)kt<<13);
    char* kd = (char*)Ks + (buf<<14) + (w<<10);
    char* vd = (char*)Vs + (buf<<14) + (w<<10);
    #pragma unroll
    for (int j=0;j<2;j++){
      GLOAD16(ks  + kOff[j], kd + (j<<13));
      GLOAD16(vs_ + vOff[j], vd + (j<<13));
    }
  };
  auto stage_paged = [&](int T, int buf){
    const size_t pb  = ((((size_t)(T>>2)<<3) + (size_t)b)*16 + (size_t)h) << 15;
    const size_t off = (size_t)(T&3)<<13;
    const float* kp = kpf + pb + off;
    const float* vp = vpf + pb + off;
    float4 kr[4], vr_[4];
    #pragma unroll
    for (int j=0;j<4;j++) kr[j]  = *reinterpret_cast<const float4*>(kp + ksrc[j]);
    #pragma unroll
    for (int j=0;j<4;j++) vr_[j] = *reinterpret_cast<const float4*>(vp + vsrc[j]);
    char* kd = (char*)Ks + (buf<<14);
    char* vd = (char*)Vs + (buf<<14);
    #pragma unroll
    for (int j=0;j<4;j++){
      bf16x4 o4; o4[0]=(bf16)kr[j].x; o4[1]=(bf16)kr[j].y; o4[2]=(bf16)kr[j].z; o4[3]=(bf16)kr[j].w;
      *reinterpret_cast<bf16x4*>(kd + ((t + (j<<9))<<3)) = o4;
    }
    #pragma unroll
    for (int j=0;j<4;j++){
      bf16x4 o4; o4[0]=(bf16)vr_[j].x; o4[1]=(bf16)vr_[j].y; o4[2]=(bf16)vr_[j].z; o4[3]=(bf16)vr_[j].w;
      *reinterpret_cast<bf16x4*>(vd + ((t + (j<<9))<<3)) = o4;
    }
  };

  auto process = [&](int buf, int lo, int hi, bool masked, bool causal, int ktg){
    const char* Kb = (const char*)Ks + (buf<<14);
    as3_char* vbL = (as3_char*)((as3_char*)Vs + (buf<<14) + voffL);
    f32x4 s[4] = {};
    #pragma unroll
    for (int kc=0;kc<4;kc++){
      const char* bk = Kb + kbase[kc];
      bf16x8 kf[4];
      #pragma unroll
      for (int cb=0;cb<4;cb++)
        kf[cb] = *reinterpret_cast<const bf16x8*>(bk + (cb<<12));
      __builtin_amdgcn_s_setprio(1);
      #pragma unroll
      for (int cb=0;cb<4;cb++)
        s[cb] = __builtin_amdgcn_mfma_f32_16x16x32_bf16(kf[cb], qf[kc], s[cb], 0,0,0);
      __builtin_amdgcn_s_setprio(0);
    }
    if (masked){
      #pragma unroll
      for (int cb=0;cb<4;cb++)
        #pragma unroll
        for (int ri=0;ri<4;ri++){
          const int kvl = (cb<<4) + (g<<2) + ri;
          bool ok = (kvl >= lo) && (kvl < hi);
          if (causal) ok = ok && ((ktg + kvl) <= (q0w + c));
          s[cb][ri] = ok ? s[cb][ri] : -3e38f;
        }
    }
    {
      float m0_ = fmaxf(fmaxf(s[0][0], s[0][1]), fmaxf(s[0][2], s[0][3]));
      float m1_ = fmaxf(fmaxf(s[1][0], s[1][1]), fmaxf(s[1][2], s[1][3]));
      float m2_ = fmaxf(fmaxf(s[2][0], s[2][1]), fmaxf(s[2][2], s[2][3]));
      float m3_ = fmaxf(fmaxf(s[3][0], s[3][1]), fmaxf(s[3][2], s[3][3]));
      float mx = fmaxf(fmaxf(m0_, m1_), fmaxf(m2_, m3_));
      const int defer = __all(mx - mrow <= 11.5f);
      if (!defer){
        float mr = fmaxf(mx, __shfl_xor(mx, 16, 64));
        mr = fmaxf(mr, __shfl_xor(mr, 32, 64));
        const float mn = fmaxf(mrow, mr);
        const float al = exp2f(mrow - mn);
        mrow = mn;
        lsum *= al;
        #pragma unroll
        for (int ri=0;ri<4;ri++){
          const float av = __shfl(al, (l&48) | ((g<<2)+ri), 64);
          #pragma unroll
          for (int dcb=0;dcb<8;dcb++) o[dcb][ri] *= av;
        }
      }
      float ps = 0.f;
      #pragma unroll
      for (int cb=0;cb<4;cb++)
        #pragma unroll
        for (int ri=0;ri<4;ri++){
          const float e = exp2f(s[cb][ri] - mrow);
          s[cb][ri] = e; ps += e;
        }
      lsum += ps;
    }
    {
      u16x4 vr0[4], vr1[4];
      bf16x8 pav;
      union { unsigned short us[8]; bf16x8 v; } uu;
      #pragma unroll
      for (int e=0;e<8;e++) pav[e] = (bf16)s[e>>2][e&3];
      TRRD(vr0[0],vr1[0],"0","1024");  TRRD(vr0[1],vr1[1],"128","1152");
      TRRD(vr0[2],vr1[2],"256","1280");TRRD(vr0[3],vr1[3],"384","1408");
      asm volatile("s_waitcnt lgkmcnt(0)" ::: "memory");
      __builtin_amdgcn_sched_barrier(0);
      __builtin_amdgcn_s_setprio(1);
      #pragma unroll
      for (int d4=0;d4<4;d4++){
        #pragma unroll
        for (int i=0;i<4;i++){ uu.us[i]=vr0[d4][i]; uu.us[4+i]=vr1[d4][i]; }
        o[d4] = __builtin_amdgcn_mfma_f32_16x16x32_bf16(pav, uu.v, o[d4], 0,0,0);
      }
      __builtin_amdgcn_s_setprio(0);
      TRRD(vr0[0],vr1[0],"512","1536");  TRRD(vr0[1],vr1[1],"640","1664");
      TRRD(vr0[2],vr1[2],"768","1792");  TRRD(vr0[3],vr1[3],"896","1920");
      asm volatile("s_waitcnt lgkmcnt(0)" ::: "memory");
      __builtin_amdgcn_sched_barrier(0);
      __builtin_amdgcn_s_setprio(1);
      #pragma unroll
      for (int d4=0;d4<4;d4++){
        #pragma unroll
        for (int i=0;i<4;i++){ uu.us[i]=vr0[d4][i]; uu.us[4+i]=vr1[d4][i]; }
        o[4+d4] = __builtin_amdgcn_mfma_f32_16x16x32_bf16(pav, uu.v, o[4+d4], 0,0,0);
      }
      __builtin_amdgcn_s_setprio(0);
      #pragma unroll
      for (int e=0;e<8;e++) pav[e] = (bf16)s[2+(e>>2)][e&3];
      TRRD(vr0[0],vr1[0],"8192","9216"); TRRD(vr0[1],vr1[1],"8320","9344");
      TRRD(vr0[2],vr1[2],"8448","9472"); TRRD(vr0[3],vr1[3],"8576","9600");
      asm volatile("s_waitcnt lgkmcnt(0)" ::: "memory");
      __builtin_amdgcn_sched_barrier(0);
      __builtin_amdgcn_s_setprio(1);
      #pragma unroll
      for (int d4=0;d4<4;d4++){
        #pragma unroll
        for (int i=0;i<4;i++){ uu.us[i]=vr0[d4][i]; uu.us[4+i]=vr1[d4][i]; }
        o[d4] = __builtin_amdgcn_mfma_f32_16x16x32_bf16(pav, uu.v, o[d4], 0,0,0);
      }
      __builtin_amdgcn_s_setprio(0);
      TRRD(vr0[0],vr1[0],"8704","9728"); TRRD(vr0[1],vr1[1],"8832","9856");
      TRRD(vr0[2],vr1[2],"8960","9984"); TRRD(vr0[3],vr1[3],"9088","10112");
      asm volatile("s_waitcnt lgkmcnt(0)" ::: "memory");
      __builtin_amdgcn_sched_barrier(0);
      __builtin_amdgcn_s_setprio(1);
      #pragma unroll
      for (int d4=0;d4<4;d4++){
        #pragma unroll
        for (int i=0;i<4;i++){ uu.us[i]=vr0[d4][i]; uu.us[4+i]=vr1[d4][i]; }
        o[4+d4] = __builtin_amdgcn_mfma_f32_16x16x32_bf16(pav, uu.v, o[4+d4], 0,0,0);
      }
      __builtin_amdgcn_s_setprio(0);
    }
  };

  int buf = 0;
  stage_paged(0, 0);
  __syncthreads();
  for (int T=0; T<NT; ++T){
    const bool pre = (T+1 < NT);
    const bool np  = pre && (T+1 < 32);
    if (pre && !np) stage_causal(T+1, buf^1);
    int lo=0, hi=64, ktg=0; bool causal=false, masked=false, skip=false;
    if (T < 32){
      const int pg = T>>2, to = T&3;
      const int start = page_pos[(pg*8+b)*2], plen = page_pos[(pg*8+b)*2+1];
      lo = start - (to<<6); hi = start + plen - (to<<6); if (hi>64) hi=64;
      masked = (lo > 0) || (hi < 64);
      skip = (hi <= 0) || (lo >= 64);
    } else {
      const int kt = T-32; ktg = kt<<6;
      hi = len_b - ktg; if (hi>64) hi=64;
      skip = (ktg > q0w + 15) || (hi <= 0);
      causal = (ktg + 63 > q0w);
      masked = causal || (hi < 64);
    }
    if (!skip) process(buf, lo, hi, masked, causal, ktg);
    if (np) stage_paged(T+1, buf^1);
    asm volatile("s_waitcnt vmcnt(0)" ::: "memory");
    __syncthreads();
    buf ^= 1;
  }

  {
    float tl = lsum;
    tl += __shfl_xor(tl, 16, 64);
    tl += __shfl_xor(tl, 32, 64);
    const float inv = 1.f / fmaxf(tl, 1e-9f);
    #pragma unroll
    for (int ri=0;ri<4;ri++){
      const float iv = __shfl(inv, (l&48) | ((g<<2)+ri), 64);
      const int q = q0w + (g<<2) + ri;
      #pragma unroll
      for (int dcb=0;dcb<8;dcb++)
        ctx[(((size_t)(b<<10) + q)<<11) + (h<<7) + (dcb<<4) + c] = (bf16)(o[dcb][ri]*iv);
    }
  }
}

// ---------------- launcher ----------------
extern "C" void kernel_launch(void* const* d_in, const int* in_sizes, int n_in,
                              void* d_out, int out_size, void* d_ws, size_t ws_size,
                              hipStream_t stream)
{
  const float* hidden  = (const float*)d_in[0];
  const float* W_attn  = (const float*)d_in[1];
  const float* b_attn  = (const float*)d_in[2];
  const float* W_proj  = (const float*)d_in[3];
  const float* b_proj  = (const float*)d_in[4];
  const float* k_pages = (const float*)d_in[5];
  const float* v_pages = (const float*)d_in[6];
  const int*   page_pos  = (const int*)d_in[7];
  const int*   input_pos = (const int*)d_in[8];
  float* out = (float*)d_out;
  char* ws = (char*)d_ws;
  bf16* A1  = (bf16*)(ws);              // 8192x2048 bf16 (32MB); reused as ctx
  bf16* Wt1 = (bf16*)(ws + 33554432);   // 6144x2048 bf16 (24MB)
  bf16* Wt2 = (bf16*)(ws + 58720256);   // 2048x2048 bf16 (8MB)
  bf16* qb  = (bf16*)(ws + 67108864);   // [8,16,1024,128] bf16 (32MB)
  bf16* kb  = (bf16*)(ws + 100663296);
  bf16* vb  = (bf16*)(ws + 134217728);  // end 167,772,160
  bf16* ctx = A1;

  k_cvt_bf16<<<16384, 256, 0, stream>>>(hidden, A1, 4194304);
  k_transpose_cvt2<<<dim3(256,64), 256, 0, stream>>>(W_attn, Wt1, W_proj, Wt2);
  k_gemm8<0><<<768, 512, 0, stream>>>(A1, Wt1, b_attn, 6144, 2048, qb, kb, vb, nullptr);
  k_attn<<<1024, 512, 0, stream>>>(qb, kb, vb, k_pages, v_pages, page_pos, input_pos, ctx);
  k_gemm8<1><<<256, 512, 0, stream>>>(ctx, Wt2, b_proj, 2048, 2048, nullptr, nullptr, nullptr, out);
}

// Round 19
// 623.662 us; speedup vs baseline: 1.8775x; 1.0107x over previous
//
#include <hip/hip_runtime.h>

typedef __bf16 bf16;
typedef __bf16 bf16x8 __attribute__((ext_vector_type(8)));
typedef __bf16 bf16x4 __attribute__((ext_vector_type(4)));
typedef float f32x4 __attribute__((ext_vector_type(4)));
typedef unsigned short u16x4 __attribute__((ext_vector_type(4)));
typedef __attribute__((address_space(3))) const void as3_void;
typedef __attribute__((address_space(3))) const char as3_char;

#define GLOAD16(G,L) __builtin_amdgcn_global_load_lds((__attribute__((address_space(1))) const void*)(G), (__attribute__((address_space(3))) void*)(L), 16, 0, 0)

// ---------------- fused preamble: hidden f32->bf16 cvt + both weight transposes ----------------
__global__ void k_pre(const float* __restrict__ hidden, bf16* __restrict__ A1,
                      const float* __restrict__ WA, bf16* __restrict__ Wt1,
                      const float* __restrict__ WP, bf16* __restrict__ Wt2){
  __shared__ float tile[32][33];
  if (blockIdx.x < 16384){
    int i = blockIdx.x*256 + threadIdx.x;
    float4 v = reinterpret_cast<const float4*>(hidden)[i];
    bf16x4 o; o[0]=(bf16)v.x; o[1]=(bf16)v.y; o[2]=(bf16)v.z; o[3]=(bf16)v.w;
    reinterpret_cast<bf16x4*>(A1)[i] = o;
    return;
  }
  const int tb = blockIdx.x - 16384;
  const int bx = tb & 255, by = tb >> 8;      // 256 x 64
  const int K = 2048;
  const bool isA = (bx < 192);
  const float* src = isA ? WA : WP;
  bf16* dst = isA ? Wt1 : Wt2;
  const int N = isA ? 6144 : 2048;
  int n0 = (isA ? bx : (bx - 192))*32, k0 = by*32;
  int tx = threadIdx.x & 31, ty = threadIdx.x >> 5; // 32 x 8
  #pragma unroll
  for (int i=0;i<32;i+=8)
    tile[ty+i][tx] = src[(size_t)(k0+ty+i)*N + n0+tx];
  __syncthreads();
  #pragma unroll
  for (int i=0;i<32;i+=8)
    dst[(size_t)(n0+ty+i)*K + k0+tx] = (bf16)tile[tx][ty+i];
}

// ---------------- 256x256 bf16 MFMA GEMM, 8 waves, BK=64, 4-phase K-tile schedule ----------------
template<int EPI>
__global__ __launch_bounds__(512,2) void k_gemm8(
    const bf16* __restrict__ A, const bf16* __restrict__ Bt,
    const float* __restrict__ bias, int N, int K,
    bf16* __restrict__ q_out, bf16* __restrict__ k_out, bf16* __restrict__ v_out,
    float* __restrict__ c_out)
{
  __shared__ bf16 S[2][4][8192];   // [buf][A0,A1,B0,B1][128*64]
  const int t = threadIdx.x, w = t>>6, l = t&63, g = l>>4, c = l&15;
  const int wm = w>>2, wn = w&3;   // 2M x 4N waves
  const int nb = N>>8;
  const int cpx = gridDim.x>>3;
  const int swz = (blockIdx.x&7)*cpx + (blockIdx.x>>3);   // XCD swizzle (grid%8==0)
  const int m0 = (swz/nb)<<8, n0 = (swz%nb)<<8;
  const int NK = K>>6;

  int abase[2];
  #pragma unroll
  for (int kk=0; kk<2; ++kk)
    abase[kk] = (c<<7) + (((((kk<<2)|g)) ^ (c&7))<<4);

  const int r0 = t>>3;
  const int col0 = ((t&7) ^ (r0&7))<<3;

  auto stageA = [&](int kt2){
    #pragma unroll
    for (int hh=0; hh<2; ++hh){
      const bf16* sp = A + (size_t)(m0 + hh*128)*K + (kt2<<6);
      char* dp = (char*)&S[kt2&1][hh][0];
      GLOAD16(sp + (size_t)r0*K + col0,      dp + t*16);
      GLOAD16(sp + (size_t)(r0+64)*K + col0, dp + (t+512)*16);
    }
  };
  auto stageB = [&](int kt2){
    #pragma unroll
    for (int hh=0; hh<2; ++hh){
      const bf16* sp = Bt + (size_t)(n0 + hh*128)*K + (kt2<<6);
      char* dp = (char*)&S[kt2&1][2+hh][0];
      GLOAD16(sp + (size_t)r0*K + col0,      dp + t*16);
      GLOAD16(sp + (size_t)(r0+64)*K + col0, dp + (t+512)*16);
    }
  };

  f32x4 acc[8][4] = {};

  stageA(0); stageB(0);
  asm volatile("s_waitcnt vmcnt(0)" ::: "memory");
  __builtin_amdgcn_s_barrier();

  for (int kt=0; kt<NK; ++kt){
    const int bufc = kt&1;
    const char* Ab_ = (const char*)&S[bufc][wm][0];
    const char* Bb_ = (const char*)&S[bufc][2+(wn>>1)][0] + ((wn&1)<<13);
    const bool pre = (kt+1 < NK);
    bf16x8 af[4][2], bfr[2][2];

    auto lda = [&](int mh){
      #pragma unroll
      for (int mf=0; mf<4; ++mf)
        #pragma unroll
        for (int kk=0; kk<2; ++kk)
          af[mf][kk] = *reinterpret_cast<const bf16x8*>(Ab_ + abase[kk] + mh*8192 + mf*2048);
    };
    auto ldb = [&](int nh){
      #pragma unroll
      for (int nf=0; nf<2; ++nf)
        #pragma unroll
        for (int kk=0; kk<2; ++kk)
          bfr[nf][kk] = *reinterpret_cast<const bf16x8*>(Bb_ + abase[kk] + nh*4096 + nf*2048);
    };
    auto cluster = [&](int mh, int nh){
      __builtin_amdgcn_s_barrier();
      asm volatile("s_waitcnt lgkmcnt(0)" ::: "memory");
      __builtin_amdgcn_sched_barrier(0);
      __builtin_amdgcn_s_setprio(1);
      #pragma unroll
      for (int mf=0; mf<4; ++mf)
        #pragma unroll
        for (int nf=0; nf<2; ++nf)
          #pragma unroll
          for (int kk=0; kk<2; ++kk)
            acc[mh*4+mf][nh*2+nf] =
              __builtin_amdgcn_mfma_f32_16x16x32_bf16(af[mf][kk], bfr[nf][kk], acc[mh*4+mf][nh*2+nf], 0,0,0);
      __builtin_amdgcn_s_setprio(0);
    };

    lda(0); ldb(0);
    if (pre) stageA(kt+1);
    cluster(0,0);
    __builtin_amdgcn_s_barrier();
    ldb(1);
    if (pre) stageB(kt+1);
    cluster(0,1);
    __builtin_amdgcn_s_barrier();
    lda(1);
    cluster(1,1);
    __builtin_amdgcn_s_barrier();
    ldb(0);
    cluster(1,0);
    asm volatile("s_waitcnt vmcnt(0)" ::: "memory");
    __builtin_amdgcn_s_barrier();
  }

  if constexpr (EPI==0){
    #pragma unroll
    for (int NF=0; NF<4; ++NF){
      const int col = n0 + wn*64 + NF*16 + c;
      const int sec = col>>11; const int rem = col&2047;
      const int hhd = rem>>7;  const int dd = rem&127;
      bf16* dst = (sec==0) ? q_out : ((sec==1) ? k_out : v_out);
      const float bv = bias[col];
      const float qs = (sec==0) ? 0.12751743f : 1.0f;  // pre-scale Q: 1/sqrt(128)*log2(e)
      #pragma unroll
      for (int MF=0; MF<8; ++MF)
        #pragma unroll
        for (int ri=0; ri<4; ++ri){
          const int row = m0 + wm*128 + MF*16 + (g<<2) + ri;
          const int bb = row>>10, qp = row&1023;
          dst[(((size_t)(bb*16+hhd)*1024 + qp)<<7) + dd] = (bf16)((acc[MF][NF][ri] + bv)*qs);
        }
    }
  } else {
    #pragma unroll
    for (int NF=0; NF<4; ++NF){
      const int col = n0 + wn*64 + NF*16 + c;
      const float bv = bias[col];
      #pragma unroll
      for (int MF=0; MF<8; ++MF)
        #pragma unroll
        for (int ri=0; ri<4; ++ri){
          const int row = m0 + wm*128 + MF*16 + (g<<2) + ri;
          c_out[(size_t)row*N + col] = acc[MF][NF][ri] + bv;
        }
    }
  }
}

// 2 x ds_read_b64_tr_b16 with literal offsets from the single per-tile V base (vbL, LDS addr-space)
#define TRRD(R0, R1, O0, O1) \
  asm volatile("ds_read_b64_tr_b16 %0, %2 offset:" O0 "\n\t" \
               "ds_read_b64_tr_b16 %1, %2 offset:" O1 \
               : "=&v"(R0), "=&v"(R1) : "v"(vbL) : "memory")

// ---------------- fused paged + causal flash attention ----------------
// r18 structure; CHANGE: paged staging in 16B granules — thread t's two dest units share one
// slot, so 8 source floats are contiguous (2x float4) and dest is ONE linear ds_write_b128.
// Halves LDS-write op count + staging address math (VALU was 46%).
__global__ __launch_bounds__(512) __attribute__((amdgpu_waves_per_eu(4,4))) void k_attn(
    const bf16* __restrict__ qb, const bf16* __restrict__ kb, const bf16* __restrict__ vb,
    const float* __restrict__ kpf, const float* __restrict__ vpf,
    const int* __restrict__ page_pos, const int* __restrict__ input_pos,
    bf16* __restrict__ ctx)
{
  __shared__ bf16 Ks[2*64*128];
  __shared__ bf16 Vs[2*64*128];
  const int t = threadIdx.x, w = t>>6, l = t&63, g = l>>4, c = l&15;
  const int bid = blockIdx.x;
  const int wg = (bid&7)*128 + (bid>>3);
  const int qt = wg & 7, h = (wg>>3)&15, b = wg>>7;
  const int q0w = (qt<<7) + (w<<4);
  const size_t bh = (size_t)(b*16 + h);

  const bf16* qptr = qb + (bh<<17);
  bf16x8 qf[4];
  #pragma unroll
  for (int kc=0;kc<4;kc++)
    qf[kc] = *reinterpret_cast<const bf16x8*>(qptr + ((size_t)(q0w + c)<<7) + kc*32 + (g<<3));

  int kbase[4];
  #pragma unroll
  for (int kc=0;kc<4;kc++)
    kbase[kc] = (c<<8) + ((((kc<<2)|g) ^ c)<<4);
  const int voffL = (g<<11) + (c<<3);   // V tr_read base offset

  // causal staging (gload_lds, 16B slots, 2/thread)
  int kOff[2], vOff[2];
  #pragma unroll
  for (int j=0;j<2;j++){
    const int slot = t + (j<<9);
    {
      const int a = slot<<4; const int r = a>>8; const int co = (a&255) ^ ((r&15)<<4);
      kOff[j] = (r<<7) + (co>>1);
    }
    {
      const int s_ = slot;
      const int p  = ((s_>>6)<<2) | ((s_>>1)&3);
      const int d0 = (((s_>>3)&7)<<4) | ((s_&1)<<3);
      const int pp = (p&32) | ((p&4)<<2) | (((p>>3)&3)<<2) | (p&3); // pi(p)
      vOff[j] = (pp<<7) + d0;
    }
  }
  // paged reg-staging: slot s_=t+i*512 covers dest bytes [s_*16, s_*16+16) -> 8 contiguous src floats
  int ksrc2[2], vsrc2[2];
  #pragma unroll
  for (int i=0;i<2;i++){
    const int s_ = t + (i<<9);
    // K: same inverse-swizzle as kOff (slot granularity)
    {
      const int a = s_<<4; const int r = a>>8; const int co = (a&255) ^ ((r&15)<<4);
      ksrc2[i] = (r<<7) + (co>>1);
    }
    // V: same subtile map as vOff (slot granularity)
    {
      const int p  = ((s_>>6)<<2) | ((s_>>1)&3);
      const int d0 = (((s_>>3)&7)<<4) | ((s_&1)<<3);
      const int pp = (p&32) | ((p&4)<<2) | (((p>>3)&3)<<2) | (p&3);
      vsrc2[i] = (pp<<7) + d0;
    }
  }
  const bf16* kcb = kb + (bh<<17);
  const bf16* vcb = vb + (bh<<17);
  const int len_b = input_pos[b*2+1];
  const int NT = 32 + ((qt+1)<<1);

  f32x4 o[8] = {};
  float mrow = -1e38f;
  float lsum = 0.f;

  auto stage_causal = [&](int T, int buf){
    const int kt = T-32;
    const bf16* ks  = kcb + ((size_t)kt<<13);
    const bf16* vs_ = vcb + ((size_t)kt<<13);
    char* kd = (char*)Ks + (buf<<14) + (w<<10);
    char* vd = (char*)Vs + (buf<<14) + (w<<10);
    #pragma unroll
    for (int j=0;j<2;j++){
      GLOAD16(ks  + kOff[j], kd + (j<<13));
      GLOAD16(vs_ + vOff[j], vd + (j<<13));
    }
  };
  auto stage_paged = [&](int T, int buf){
    const size_t pb  = ((((size_t)(T>>2)<<3) + (size_t)b)*16 + (size_t)h) << 15;
    const size_t off = (size_t)(T&3)<<13;
    const float* kp = kpf + pb + off;
    const float* vp = vpf + pb + off;
    float4 ka[2][2], va[2][2];
    #pragma unroll
    for (int i=0;i<2;i++){
      ka[i][0] = *reinterpret_cast<const float4*>(kp + ksrc2[i]);
      ka[i][1] = *reinterpret_cast<const float4*>(kp + ksrc2[i] + 4);
      va[i][0] = *reinterpret_cast<const float4*>(vp + vsrc2[i]);
      va[i][1] = *reinterpret_cast<const float4*>(vp + vsrc2[i] + 4);
    }
    char* kd = (char*)Ks + (buf<<14);
    char* vd = (char*)Vs + (buf<<14);
    #pragma unroll
    for (int i=0;i<2;i++){
      bf16x8 o8;
      o8[0]=(bf16)ka[i][0].x; o8[1]=(bf16)ka[i][0].y; o8[2]=(bf16)ka[i][0].z; o8[3]=(bf16)ka[i][0].w;
      o8[4]=(bf16)ka[i][1].x; o8[5]=(bf16)ka[i][1].y; o8[6]=(bf16)ka[i][1].z; o8[7]=(bf16)ka[i][1].w;
      *reinterpret_cast<bf16x8*>(kd + ((t + (i<<9))<<4)) = o8;
      bf16x8 v8;
      v8[0]=(bf16)va[i][0].x; v8[1]=(bf16)va[i][0].y; v8[2]=(bf16)va[i][0].z; v8[3]=(bf16)va[i][0].w;
      v8[4]=(bf16)va[i][1].x; v8[5]=(bf16)va[i][1].y; v8[6]=(bf16)va[i][1].z; v8[7]=(bf16)va[i][1].w;
      *reinterpret_cast<bf16x8*>(vd + ((t + (i<<9))<<4)) = v8;
    }
  };

  auto process = [&](int buf, int lo, int hi, bool masked, bool causal, int ktg){
    const char* Kb = (const char*)Ks + (buf<<14);
    as3_char* vbL = (as3_char*)((as3_char*)Vs + (buf<<14) + voffL);
    f32x4 s[4] = {};
    #pragma unroll
    for (int kc=0;kc<4;kc++){
      const char* bk = Kb + kbase[kc];
      bf16x8 kf[4];
      #pragma unroll
      for (int cb=0;cb<4;cb++)
        kf[cb] = *reinterpret_cast<const bf16x8*>(bk + (cb<<12));
      __builtin_amdgcn_s_setprio(1);
      #pragma unroll
      for (int cb=0;cb<4;cb++)
        s[cb] = __builtin_amdgcn_mfma_f32_16x16x32_bf16(kf[cb], qf[kc], s[cb], 0,0,0);
      __builtin_amdgcn_s_setprio(0);
    }
    if (masked){
      #pragma unroll
      for (int cb=0;cb<4;cb++)
        #pragma unroll
        for (int ri=0;ri<4;ri++){
          const int kvl = (cb<<4) + (g<<2) + ri;
          bool ok = (kvl >= lo) && (kvl < hi);
          if (causal) ok = ok && ((ktg + kvl) <= (q0w + c));
          s[cb][ri] = ok ? s[cb][ri] : -3e38f;
        }
    }
    {
      float m0_ = fmaxf(fmaxf(s[0][0], s[0][1]), fmaxf(s[0][2], s[0][3]));
      float m1_ = fmaxf(fmaxf(s[1][0], s[1][1]), fmaxf(s[1][2], s[1][3]));
      float m2_ = fmaxf(fmaxf(s[2][0], s[2][1]), fmaxf(s[2][2], s[2][3]));
      float m3_ = fmaxf(fmaxf(s[3][0], s[3][1]), fmaxf(s[3][2], s[3][3]));
      float mx = fmaxf(fmaxf(m0_, m1_), fmaxf(m2_, m3_));
      const int defer = __all(mx - mrow <= 11.5f);
      if (!defer){
        float mr = fmaxf(mx, __shfl_xor(mx, 16, 64));
        mr = fmaxf(mr, __shfl_xor(mr, 32, 64));
        const float mn = fmaxf(mrow, mr);
        const float al = exp2f(mrow - mn);
        mrow = mn;
        lsum *= al;
        #pragma unroll
        for (int ri=0;ri<4;ri++){
          const float av = __shfl(al, (l&48) | ((g<<2)+ri), 64);
          #pragma unroll
          for (int dcb=0;dcb<8;dcb++) o[dcb][ri] *= av;
        }
      }
      float ps = 0.f;
      #pragma unroll
      for (int cb=0;cb<4;cb++)
        #pragma unroll
        for (int ri=0;ri<4;ri++){
          const float e = exp2f(s[cb][ri] - mrow);
          s[cb][ri] = e; ps += e;
        }
      lsum += ps;
    }
    {
      u16x4 vr0[4], vr1[4];
      bf16x8 pav;
      union { unsigned short us[8]; bf16x8 v; } uu;
      #pragma unroll
      for (int e=0;e<8;e++) pav[e] = (bf16)s[e>>2][e&3];
      TRRD(vr0[0],vr1[0],"0","1024");  TRRD(vr0[1],vr1[1],"128","1152");
      TRRD(vr0[2],vr1[2],"256","1280");TRRD(vr0[3],vr1[3],"384","1408");
      asm volatile("s_waitcnt lgkmcnt(0)" ::: "memory");
      __builtin_amdgcn_sched_barrier(0);
      __builtin_amdgcn_s_setprio(1);
      #pragma unroll
      for (int d4=0;d4<4;d4++){
        #pragma unroll
        for (int i=0;i<4;i++){ uu.us[i]=vr0[d4][i]; uu.us[4+i]=vr1[d4][i]; }
        o[d4] = __builtin_amdgcn_mfma_f32_16x16x32_bf16(pav, uu.v, o[d4], 0,0,0);
      }
      __builtin_amdgcn_s_setprio(0);
      TRRD(vr0[0],vr1[0],"512","1536");  TRRD(vr0[1],vr1[1],"640","1664");
      TRRD(vr0[2],vr1[2],"768","1792");  TRRD(vr0[3],vr1[3],"896","1920");
      asm volatile("s_waitcnt lgkmcnt(0)" ::: "memory");
      __builtin_amdgcn_sched_barrier(0);
      __builtin_amdgcn_s_setprio(1);
      #pragma unroll
      for (int d4=0;d4<4;d4++){
        #pragma unroll
        for (int i=0;i<4;i++){ uu.us[i]=vr0[d4][i]; uu.us[4+i]=vr1[d4][i]; }
        o[4+d4] = __builtin_amdgcn_mfma_f32_16x16x32_bf16(pav, uu.v, o[4+d4], 0,0,0);
      }
      __builtin_amdgcn_s_setprio(0);
      #pragma unroll
      for (int e=0;e<8;e++) pav[e] = (bf16)s[2+(e>>2)][e&3];
      TRRD(vr0[0],vr1[0],"8192","9216"); TRRD(vr0[1],vr1[1],"8320","9344");
      TRRD(vr0[2],vr1[2],"8448","9472"); TRRD(vr0[3],vr1[3],"8576","9600");
      asm volatile("s_waitcnt lgkmcnt(0)" ::: "memory");
      __builtin_amdgcn_sched_barrier(0);
      __builtin_amdgcn_s_setprio(1);
      #pragma unroll
      for (int d4=0;d4<4;d4++){
        #pragma unroll
        for (int i=0;i<4;i++){ uu.us[i]=vr0[d4][i]; uu.us[4+i]=vr1[d4][i]; }
        o[d4] = __builtin_amdgcn_mfma_f32_16x16x32_bf16(pav, uu.v, o[d4], 0,0,0);
      }
      __builtin_amdgcn_s_setprio(0);
      TRRD(vr0[0],vr1[0],"8704","9728"); TRRD(vr0[1],vr1[1],"8832","9856");
      TRRD(vr0[2],vr1[2],"8960","9984"); TRRD(vr0[3],vr1[3],"9088","10112");
      asm volatile("s_waitcnt lgkmcnt(0)" ::: "memory");
      __builtin_amdgcn_sched_barrier(0);
      __builtin_amdgcn_s_setprio(1);
      #pragma unroll
      for (int d4=0;d4<4;d4++){
        #pragma unroll
        for (int i=0;i<4;i++){ uu.us[i]=vr0[d4][i]; uu.us[4+i]=vr1[d4][i]; }
        o[4+d4] = __builtin_amdgcn_mfma_f32_16x16x32_bf16(pav, uu.v, o[4+d4], 0,0,0);
      }
      __builtin_amdgcn_s_setprio(0);
    }
  };

  int buf = 0;
  stage_paged(0, 0);
  __syncthreads();
  for (int T=0; T<NT; ++T){
    const bool pre = (T+1 < NT);
    const bool np  = pre && (T+1 < 32);
    if (pre && !np) stage_causal(T+1, buf^1);
    int lo=0, hi=64, ktg=0; bool causal=false, masked=false, skip=false;
    if (T < 32){
      const int pg = T>>2, to = T&3;
      const int start = page_pos[(pg*8+b)*2], plen = page_pos[(pg*8+b)*2+1];
      lo = start - (to<<6); hi = start + plen - (to<<6); if (hi>64) hi=64;
      masked = (lo > 0) || (hi < 64);
      skip = (hi <= 0) || (lo >= 64);
    } else {
      const int kt = T-32; ktg = kt<<6;
      hi = len_b - ktg; if (hi>64) hi=64;
      skip = (ktg > q0w + 15) || (hi <= 0);
      causal = (ktg + 63 > q0w);
      masked = causal || (hi < 64);
    }
    if (!skip) process(buf, lo, hi, masked, causal, ktg);
    if (np) stage_paged(T+1, buf^1);
    asm volatile("s_waitcnt vmcnt(0)" ::: "memory");
    __syncthreads();
    buf ^= 1;
  }

  {
    float tl = lsum;
    tl += __shfl_xor(tl, 16, 64);
    tl += __shfl_xor(tl, 32, 64);
    const float inv = 1.f / fmaxf(tl, 1e-9f);
    #pragma unroll
    for (int ri=0;ri<4;ri++){
      const float iv = __shfl(inv, (l&48) | ((g<<2)+ri), 64);
      const int q = q0w + (g<<2) + ri;
      #pragma unroll
      for (int dcb=0;dcb<8;dcb++)
        ctx[(((size_t)(b<<10) + q)<<11) + (h<<7) + (dcb<<4) + c] = (bf16)(o[dcb][ri]*iv);
    }
  }
}

// ---------------- launcher ----------------
extern "C" void kernel_launch(void* const* d_in, const int* in_sizes, int n_in,
                              void* d_out, int out_size, void* d_ws, size_t ws_size,
                              hipStream_t stream)
{
  const float* hidden  = (const float*)d_in[0];
  const float* W_attn  = (const float*)d_in[1];
  const float* b_attn  = (const float*)d_in[2];
  const float* W_proj  = (const float*)d_in[3];
  const float* b_proj  = (const float*)d_in[4];
  const float* k_pages = (const float*)d_in[5];
  const float* v_pages = (const float*)d_in[6];
  const int*   page_pos  = (const int*)d_in[7];
  const int*   input_pos = (const int*)d_in[8];
  float* out = (float*)d_out;
  char* ws = (char*)d_ws;
  bf16* A1  = (bf16*)(ws);              // 8192x2048 bf16 (32MB); reused as ctx
  bf16* Wt1 = (bf16*)(ws + 33554432);   // 6144x2048 bf16 (24MB)
  bf16* Wt2 = (bf16*)(ws + 58720256);   // 2048x2048 bf16 (8MB)
  bf16* qb  = (bf16*)(ws + 67108864);   // [8,16,1024,128] bf16 (32MB)
  bf16* kb  = (bf16*)(ws + 100663296);
  bf16* vb  = (bf16*)(ws + 134217728);  // end 167,772,160
  bf16* ctx = A1;

  k_pre<<<32768, 256, 0, stream>>>(hidden, A1, W_attn, Wt1, W_proj, Wt2);
  k_gemm8<0><<<768, 512, 0, stream>>>(A1, Wt1, b_attn, 6144, 2048, qb, kb, vb, nullptr);
  k_attn<<<1024, 512, 0, stream>>>(qb, kb, vb, k_pages, v_pages, page_pos, input_pos, ctx);
  k_gemm8<1><<<256, 512, 0, stream>>>(ctx, Wt2, b_proj, 2048, 2048, nullptr, nullptr, nullptr, out);
}

// Round 20
// 616.156 us; speedup vs baseline: 1.9003x; 1.0122x over previous
//
#include <hip/hip_runtime.h>

typedef __bf16 bf16;
typedef __bf16 bf16x8 __attribute__((ext_vector_type(8)));
typedef __bf16 bf16x4 __attribute__((ext_vector_type(4)));
typedef float f32x4 __attribute__((ext_vector_type(4)));
typedef unsigned short u16x4 __attribute__((ext_vector_type(4)));
typedef __attribute__((address_space(3))) const void as3_void;
typedef __attribute__((address_space(3))) const char as3_char;

#define GLOAD16(G,L) __builtin_amdgcn_global_load_lds((__attribute__((address_space(1))) const void*)(G), (__attribute__((address_space(3))) void*)(L), 16, 0, 0)

// ---------------- fused preamble: hidden f32->bf16 cvt + both weight transposes ----------------
__global__ void k_pre(const float* __restrict__ hidden, bf16* __restrict__ A1,
                      const float* __restrict__ WA, bf16* __restrict__ Wt1,
                      const float* __restrict__ WP, bf16* __restrict__ Wt2){
  __shared__ float tile[32][33];
  if (blockIdx.x < 16384){
    int i = blockIdx.x*256 + threadIdx.x;
    float4 v = reinterpret_cast<const float4*>(hidden)[i];
    bf16x4 o; o[0]=(bf16)v.x; o[1]=(bf16)v.y; o[2]=(bf16)v.z; o[3]=(bf16)v.w;
    reinterpret_cast<bf16x4*>(A1)[i] = o;
    return;
  }
  const int tb = blockIdx.x - 16384;
  const int bx = tb & 255, by = tb >> 8;      // 256 x 64
  const int K = 2048;
  const bool isA = (bx < 192);
  const float* src = isA ? WA : WP;
  bf16* dst = isA ? Wt1 : Wt2;
  const int N = isA ? 6144 : 2048;
  int n0 = (isA ? bx : (bx - 192))*32, k0 = by*32;
  int tx = threadIdx.x & 31, ty = threadIdx.x >> 5; // 32 x 8
  #pragma unroll
  for (int i=0;i<32;i+=8)
    tile[ty+i][tx] = src[(size_t)(k0+ty+i)*N + n0+tx];
  __syncthreads();
  #pragma unroll
  for (int i=0;i<32;i+=8)
    dst[(size_t)(n0+ty+i)*K + k0+tx] = (bf16)tile[tx][ty+i];
}

// ---------------- 256x256 bf16 MFMA GEMM, 8 waves, BK=64, 4-phase K-tile schedule ----------------
template<int EPI>
__global__ __launch_bounds__(512,2) void k_gemm8(
    const bf16* __restrict__ A, const bf16* __restrict__ Bt,
    const float* __restrict__ bias, int N, int K,
    bf16* __restrict__ q_out, bf16* __restrict__ k_out, bf16* __restrict__ v_out,
    float* __restrict__ c_out)
{
  __shared__ bf16 S[2][4][8192];   // [buf][A0,A1,B0,B1][128*64]
  const int t = threadIdx.x, w = t>>6, l = t&63, g = l>>4, c = l&15;
  const int wm = w>>2, wn = w&3;   // 2M x 4N waves
  const int nb = N>>8;
  const int cpx = gridDim.x>>3;
  const int swz = (blockIdx.x&7)*cpx + (blockIdx.x>>3);   // XCD swizzle (grid%8==0)
  const int m0 = (swz/nb)<<8, n0 = (swz%nb)<<8;
  const int NK = K>>6;

  int abase[2];
  #pragma unroll
  for (int kk=0; kk<2; ++kk)
    abase[kk] = (c<<7) + (((((kk<<2)|g)) ^ (c&7))<<4);

  const int r0 = t>>3;
  const int col0 = ((t&7) ^ (r0&7))<<3;

  auto stageA = [&](int kt2){
    #pragma unroll
    for (int hh=0; hh<2; ++hh){
      const bf16* sp = A + (size_t)(m0 + hh*128)*K + (kt2<<6);
      char* dp = (char*)&S[kt2&1][hh][0];
      GLOAD16(sp + (size_t)r0*K + col0,      dp + t*16);
      GLOAD16(sp + (size_t)(r0+64)*K + col0, dp + (t+512)*16);
    }
  };
  auto stageB = [&](int kt2){
    #pragma unroll
    for (int hh=0; hh<2; ++hh){
      const bf16* sp = Bt + (size_t)(n0 + hh*128)*K + (kt2<<6);
      char* dp = (char*)&S[kt2&1][2+hh][0];
      GLOAD16(sp + (size_t)r0*K + col0,      dp + t*16);
      GLOAD16(sp + (size_t)(r0+64)*K + col0, dp + (t+512)*16);
    }
  };

  f32x4 acc[8][4] = {};

  stageA(0); stageB(0);
  asm volatile("s_waitcnt vmcnt(0)" ::: "memory");
  __builtin_amdgcn_s_barrier();

  for (int kt=0; kt<NK; ++kt){
    const int bufc = kt&1;
    const char* Ab_ = (const char*)&S[bufc][wm][0];
    const char* Bb_ = (const char*)&S[bufc][2+(wn>>1)][0] + ((wn&1)<<13);
    const bool pre = (kt+1 < NK);
    bf16x8 af[4][2], bfr[2][2];

    auto lda = [&](int mh){
      #pragma unroll
      for (int mf=0; mf<4; ++mf)
        #pragma unroll
        for (int kk=0; kk<2; ++kk)
          af[mf][kk] = *reinterpret_cast<const bf16x8*>(Ab_ + abase[kk] + mh*8192 + mf*2048);
    };
    auto ldb = [&](int nh){
      #pragma unroll
      for (int nf=0; nf<2; ++nf)
        #pragma unroll
        for (int kk=0; kk<2; ++kk)
          bfr[nf][kk] = *reinterpret_cast<const bf16x8*>(Bb_ + abase[kk] + nh*4096 + nf*2048);
    };
    auto cluster = [&](int mh, int nh){
      __builtin_amdgcn_s_barrier();
      asm volatile("s_waitcnt lgkmcnt(0)" ::: "memory");
      __builtin_amdgcn_sched_barrier(0);
      __builtin_amdgcn_s_setprio(1);
      #pragma unroll
      for (int mf=0; mf<4; ++mf)
        #pragma unroll
        for (int nf=0; nf<2; ++nf)
          #pragma unroll
          for (int kk=0; kk<2; ++kk)
            acc[mh*4+mf][nh*2+nf] =
              __builtin_amdgcn_mfma_f32_16x16x32_bf16(af[mf][kk], bfr[nf][kk], acc[mh*4+mf][nh*2+nf], 0,0,0);
      __builtin_amdgcn_s_setprio(0);
    };

    lda(0); ldb(0);
    if (pre) stageA(kt+1);
    cluster(0,0);
    __builtin_amdgcn_s_barrier();
    ldb(1);
    if (pre) stageB(kt+1);
    cluster(0,1);
    __builtin_amdgcn_s_barrier();
    lda(1);
    cluster(1,1);
    __builtin_amdgcn_s_barrier();
    ldb(0);
    cluster(1,0);
    asm volatile("s_waitcnt vmcnt(0)" ::: "memory");
    __builtin_amdgcn_s_barrier();
  }

  if constexpr (EPI==0){
    #pragma unroll
    for (int NF=0; NF<4; ++NF){
      const int col = n0 + wn*64 + NF*16 + c;
      const int sec = col>>11; const int rem = col&2047;
      const int hhd = rem>>7;  const int dd = rem&127;
      bf16* dst = (sec==0) ? q_out : ((sec==1) ? k_out : v_out);
      const float bv = bias[col];
      const float qs = (sec==0) ? 0.12751743f : 1.0f;  // pre-scale Q: 1/sqrt(128)*log2(e)
      #pragma unroll
      for (int MF=0; MF<8; ++MF)
        #pragma unroll
        for (int ri=0; ri<4; ++ri){
          const int row = m0 + wm*128 + MF*16 + (g<<2) + ri;
          const int bb = row>>10, qp = row&1023;
          dst[(((size_t)(bb*16+hhd)*1024 + qp)<<7) + dd] = (bf16)((acc[MF][NF][ri] + bv)*qs);
        }
    }
  } else {
    #pragma unroll
    for (int NF=0; NF<4; ++NF){
      const int col = n0 + wn*64 + NF*16 + c;
      const float bv = bias[col];
      #pragma unroll
      for (int MF=0; MF<8; ++MF)
        #pragma unroll
        for (int ri=0; ri<4; ++ri){
          const int row = m0 + wm*128 + MF*16 + (g<<2) + ri;
          c_out[(size_t)row*N + col] = acc[MF][NF][ri] + bv;
        }
    }
  }
}

// 2 x ds_read_b64_tr_b16 with literal offsets from the single per-tile V base (vbL, LDS addr-space)
#define TRRD(R0, R1, O0, O1) \
  asm volatile("ds_read_b64_tr_b16 %0, %2 offset:" O0 "\n\t" \
               "ds_read_b64_tr_b16 %1, %2 offset:" O1 \
               : "=&v"(R0), "=&v"(R1) : "v"(vbL) : "memory")

// ---------------- fused paged + causal flash attention ----------------
// r19 structure; CHANGE: softmax/PV software pipeline — exp of s[2..3] runs inside the first
// tr_read batch's LDS-latency shadow; pav1 pack inside the second; ps split into 2 chains.
// Pure reordering (no layout/sync/register-class changes).
__global__ __launch_bounds__(512) __attribute__((amdgpu_waves_per_eu(4,4))) void k_attn(
    const bf16* __restrict__ qb, const bf16* __restrict__ kb, const bf16* __restrict__ vb,
    const float* __restrict__ kpf, const float* __restrict__ vpf,
    const int* __restrict__ page_pos, const int* __restrict__ input_pos,
    bf16* __restrict__ ctx)
{
  __shared__ bf16 Ks[2*64*128];
  __shared__ bf16 Vs[2*64*128];
  const int t = threadIdx.x, w = t>>6, l = t&63, g = l>>4, c = l&15;
  const int bid = blockIdx.x;
  const int wg = (bid&7)*128 + (bid>>3);
  const int qt = wg & 7, h = (wg>>3)&15, b = wg>>7;
  const int q0w = (qt<<7) + (w<<4);
  const size_t bh = (size_t)(b*16 + h);

  const bf16* qptr = qb + (bh<<17);
  bf16x8 qf[4];
  #pragma unroll
  for (int kc=0;kc<4;kc++)
    qf[kc] = *reinterpret_cast<const bf16x8*>(qptr + ((size_t)(q0w + c)<<7) + kc*32 + (g<<3));

  int kbase[4];
  #pragma unroll
  for (int kc=0;kc<4;kc++)
    kbase[kc] = (c<<8) + ((((kc<<2)|g) ^ c)<<4);
  const int voffL = (g<<11) + (c<<3);   // V tr_read base offset

  // causal staging (gload_lds, 16B slots, 2/thread)
  int kOff[2], vOff[2];
  #pragma unroll
  for (int j=0;j<2;j++){
    const int slot = t + (j<<9);
    {
      const int a = slot<<4; const int r = a>>8; const int co = (a&255) ^ ((r&15)<<4);
      kOff[j] = (r<<7) + (co>>1);
    }
    {
      const int s_ = slot;
      const int p  = ((s_>>6)<<2) | ((s_>>1)&3);
      const int d0 = (((s_>>3)&7)<<4) | ((s_&1)<<3);
      const int pp = (p&32) | ((p&4)<<2) | (((p>>3)&3)<<2) | (p&3); // pi(p)
      vOff[j] = (pp<<7) + d0;
    }
  }
  // paged reg-staging: slot s_=t+i*512 covers dest bytes [s_*16, s_*16+16) -> 8 contiguous src floats
  int ksrc2[2], vsrc2[2];
  #pragma unroll
  for (int i=0;i<2;i++){
    const int s_ = t + (i<<9);
    {
      const int a = s_<<4; const int r = a>>8; const int co = (a&255) ^ ((r&15)<<4);
      ksrc2[i] = (r<<7) + (co>>1);
    }
    {
      const int p  = ((s_>>6)<<2) | ((s_>>1)&3);
      const int d0 = (((s_>>3)&7)<<4) | ((s_&1)<<3);
      const int pp = (p&32) | ((p&4)<<2) | (((p>>3)&3)<<2) | (p&3);
      vsrc2[i] = (pp<<7) + d0;
    }
  }
  const bf16* kcb = kb + (bh<<17);
  const bf16* vcb = vb + (bh<<17);
  const int len_b = input_pos[b*2+1];
  const int NT = 32 + ((qt+1)<<1);

  f32x4 o[8] = {};
  float mrow = -1e38f;
  float lsum = 0.f;

  auto stage_causal = [&](int T, int buf){
    const int kt = T-32;
    const bf16* ks  = kcb + ((size_t)kt<<13);
    const bf16* vs_ = vcb + ((size_t)kt<<13);
    char* kd = (char*)Ks + (buf<<14) + (w<<10);
    char* vd = (char*)Vs + (buf<<14) + (w<<10);
    #pragma unroll
    for (int j=0;j<2;j++){
      GLOAD16(ks  + kOff[j], kd + (j<<13));
      GLOAD16(vs_ + vOff[j], vd + (j<<13));
    }
  };
  auto stage_paged = [&](int T, int buf){
    const size_t pb  = ((((size_t)(T>>2)<<3) + (size_t)b)*16 + (size_t)h) << 15;
    const size_t off = (size_t)(T&3)<<13;
    const float* kp = kpf + pb + off;
    const float* vp = vpf + pb + off;
    float4 ka[2][2], va[2][2];
    #pragma unroll
    for (int i=0;i<2;i++){
      ka[i][0] = *reinterpret_cast<const float4*>(kp + ksrc2[i]);
      ka[i][1] = *reinterpret_cast<const float4*>(kp + ksrc2[i] + 4);
      va[i][0] = *reinterpret_cast<const float4*>(vp + vsrc2[i]);
      va[i][1] = *reinterpret_cast<const float4*>(vp + vsrc2[i] + 4);
    }
    char* kd = (char*)Ks + (buf<<14);
    char* vd = (char*)Vs + (buf<<14);
    #pragma unroll
    for (int i=0;i<2;i++){
      bf16x8 o8;
      o8[0]=(bf16)ka[i][0].x; o8[1]=(bf16)ka[i][0].y; o8[2]=(bf16)ka[i][0].z; o8[3]=(bf16)ka[i][0].w;
      o8[4]=(bf16)ka[i][1].x; o8[5]=(bf16)ka[i][1].y; o8[6]=(bf16)ka[i][1].z; o8[7]=(bf16)ka[i][1].w;
      *reinterpret_cast<bf16x8*>(kd + ((t + (i<<9))<<4)) = o8;
      bf16x8 v8;
      v8[0]=(bf16)va[i][0].x; v8[1]=(bf16)va[i][0].y; v8[2]=(bf16)va[i][0].z; v8[3]=(bf16)va[i][0].w;
      v8[4]=(bf16)va[i][1].x; v8[5]=(bf16)va[i][1].y; v8[6]=(bf16)va[i][1].z; v8[7]=(bf16)va[i][1].w;
      *reinterpret_cast<bf16x8*>(vd + ((t + (i<<9))<<4)) = v8;
    }
  };

  auto process = [&](int buf, int lo, int hi, bool masked, bool causal, int ktg){
    const char* Kb = (const char*)Ks + (buf<<14);
    as3_char* vbL = (as3_char*)((as3_char*)Vs + (buf<<14) + voffL);
    f32x4 s[4] = {};
    #pragma unroll
    for (int kc=0;kc<4;kc++){
      const char* bk = Kb + kbase[kc];
      bf16x8 kf[4];
      #pragma unroll
      for (int cb=0;cb<4;cb++)
        kf[cb] = *reinterpret_cast<const bf16x8*>(bk + (cb<<12));
      __builtin_amdgcn_s_setprio(1);
      #pragma unroll
      for (int cb=0;cb<4;cb++)
        s[cb] = __builtin_amdgcn_mfma_f32_16x16x32_bf16(kf[cb], qf[kc], s[cb], 0,0,0);
      __builtin_amdgcn_s_setprio(0);
    }
    if (masked){
      #pragma unroll
      for (int cb=0;cb<4;cb++)
        #pragma unroll
        for (int ri=0;ri<4;ri++){
          const int kvl = (cb<<4) + (g<<2) + ri;
          bool ok = (kvl >= lo) && (kvl < hi);
          if (causal) ok = ok && ((ktg + kvl) <= (q0w + c));
          s[cb][ri] = ok ? s[cb][ri] : -3e38f;
        }
    }
    {
      float m0_ = fmaxf(fmaxf(s[0][0], s[0][1]), fmaxf(s[0][2], s[0][3]));
      float m1_ = fmaxf(fmaxf(s[1][0], s[1][1]), fmaxf(s[1][2], s[1][3]));
      float m2_ = fmaxf(fmaxf(s[2][0], s[2][1]), fmaxf(s[2][2], s[2][3]));
      float m3_ = fmaxf(fmaxf(s[3][0], s[3][1]), fmaxf(s[3][2], s[3][3]));
      float mx = fmaxf(fmaxf(m0_, m1_), fmaxf(m2_, m3_));
      const int defer = __all(mx - mrow <= 11.5f);
      if (!defer){
        float mr = fmaxf(mx, __shfl_xor(mx, 16, 64));
        mr = fmaxf(mr, __shfl_xor(mr, 32, 64));
        const float mn = fmaxf(mrow, mr);
        const float al = exp2f(mrow - mn);
        mrow = mn;
        lsum *= al;
        #pragma unroll
        for (int ri=0;ri<4;ri++){
          const float av = __shfl(al, (l&48) | ((g<<2)+ri), 64);
          #pragma unroll
          for (int dcb=0;dcb<8;dcb++) o[dcb][ri] *= av;
        }
      }
    }
    // ---- softmax/PV software pipeline ----
    {
      u16x4 vr0[4], vr1[4];
      bf16x8 pav0, pav1;
      union { unsigned short us[8]; bf16x8 v; } uu;
      // exp of s[0..1] only (first half)
      float psA = 0.f, psB = 0.f;
      #pragma unroll
      for (int cb=0;cb<2;cb++)
        #pragma unroll
        for (int ri=0;ri<4;ri++){
          const float e = exp2f(s[cb][ri] - mrow);
          s[cb][ri] = e; psA += e;
        }
      #pragma unroll
      for (int e=0;e<8;e++) pav0[e] = (bf16)s[e>>2][e&3];
      // issue batch A, then hide exp of s[2..3] under its LDS latency
      TRRD(vr0[0],vr1[0],"0","1024");  TRRD(vr0[1],vr1[1],"128","1152");
      TRRD(vr0[2],vr1[2],"256","1280");TRRD(vr0[3],vr1[3],"384","1408");
      #pragma unroll
      for (int cb=2;cb<4;cb++)
        #pragma unroll
        for (int ri=0;ri<4;ri++){
          const float e = exp2f(s[cb][ri] - mrow);
          s[cb][ri] = e; psB += e;
        }
      lsum += psA + psB;
      asm volatile("s_waitcnt lgkmcnt(0)" ::: "memory");
      __builtin_amdgcn_sched_barrier(0);
      __builtin_amdgcn_s_setprio(1);
      #pragma unroll
      for (int d4=0;d4<4;d4++){
        #pragma unroll
        for (int i=0;i<4;i++){ uu.us[i]=vr0[d4][i]; uu.us[4+i]=vr1[d4][i]; }
        o[d4] = __builtin_amdgcn_mfma_f32_16x16x32_bf16(pav0, uu.v, o[d4], 0,0,0);
      }
      __builtin_amdgcn_s_setprio(0);
      // issue batch B, hide pav1 pack under its latency
      TRRD(vr0[0],vr1[0],"512","1536");  TRRD(vr0[1],vr1[1],"640","1664");
      TRRD(vr0[2],vr1[2],"768","1792");  TRRD(vr0[3],vr1[3],"896","1920");
      #pragma unroll
      for (int e=0;e<8;e++) pav1[e] = (bf16)s[2+(e>>2)][e&3];
      asm volatile("s_waitcnt lgkmcnt(0)" ::: "memory");
      __builtin_amdgcn_sched_barrier(0);
      __builtin_amdgcn_s_setprio(1);
      #pragma unroll
      for (int d4=0;d4<4;d4++){
        #pragma unroll
        for (int i=0;i<4;i++){ uu.us[i]=vr0[d4][i]; uu.us[4+i]=vr1[d4][i]; }
        o[4+d4] = __builtin_amdgcn_mfma_f32_16x16x32_bf16(pav0, uu.v, o[4+d4], 0,0,0);
      }
      __builtin_amdgcn_s_setprio(0);
      TRRD(vr0[0],vr1[0],"8192","9216"); TRRD(vr0[1],vr1[1],"8320","9344");
      TRRD(vr0[2],vr1[2],"8448","9472"); TRRD(vr0[3],vr1[3],"8576","9600");
      asm volatile("s_waitcnt lgkmcnt(0)" ::: "memory");
      __builtin_amdgcn_sched_barrier(0);
      __builtin_amdgcn_s_setprio(1);
      #pragma unroll
      for (int d4=0;d4<4;d4++){
        #pragma unroll
        for (int i=0;i<4;i++){ uu.us[i]=vr0[d4][i]; uu.us[4+i]=vr1[d4][i]; }
        o[d4] = __builtin_amdgcn_mfma_f32_16x16x32_bf16(pav1, uu.v, o[d4], 0,0,0);
      }
      __builtin_amdgcn_s_setprio(0);
      TRRD(vr0[0],vr1[0],"8704","9728"); TRRD(vr0[1],vr1[1],"8832","9856");
      TRRD(vr0[2],vr1[2],"8960","9984"); TRRD(vr0[3],vr1[3],"9088","10112");
      asm volatile("s_waitcnt lgkmcnt(0)" ::: "memory");
      __builtin_amdgcn_sched_barrier(0);
      __builtin_amdgcn_s_setprio(1);
      #pragma unroll
      for (int d4=0;d4<4;d4++){
        #pragma unroll
        for (int i=0;i<4;i++){ uu.us[i]=vr0[d4][i]; uu.us[4+i]=vr1[d4][i]; }
        o[4+d4] = __builtin_amdgcn_mfma_f32_16x16x32_bf16(pav1, uu.v, o[4+d4], 0,0,0);
      }
      __builtin_amdgcn_s_setprio(0);
    }
  };

  int buf = 0;
  stage_paged(0, 0);
  __syncthreads();
  for (int T=0; T<NT; ++T){
    const bool pre = (T+1 < NT);
    const bool np  = pre && (T+1 < 32);
    if (pre && !np) stage_causal(T+1, buf^1);
    int lo=0, hi=64, ktg=0; bool causal=false, masked=false, skip=false;
    if (T < 32){
      const int pg = T>>2, to = T&3;
      const int start = page_pos[(pg*8+b)*2], plen = page_pos[(pg*8+b)*2+1];
      lo = start - (to<<6); hi = start + plen - (to<<6); if (hi>64) hi=64;
      masked = (lo > 0) || (hi < 64);
      skip = (hi <= 0) || (lo >= 64);
    } else {
      const int kt = T-32; ktg = kt<<6;
      hi = len_b - ktg; if (hi>64) hi=64;
      skip = (ktg > q0w + 15) || (hi <= 0);
      causal = (ktg + 63 > q0w);
      masked = causal || (hi < 64);
    }
    if (!skip) process(buf, lo, hi, masked, causal, ktg);
    if (np) stage_paged(T+1, buf^1);
    asm volatile("s_waitcnt vmcnt(0)" ::: "memory");
    __syncthreads();
    buf ^= 1;
  }

  {
    float tl = lsum;
    tl += __shfl_xor(tl, 16, 64);
    tl += __shfl_xor(tl, 32, 64);
    const float inv = 1.f / fmaxf(tl, 1e-9f);
    #pragma unroll
    for (int ri=0;ri<4;ri++){
      const float iv = __shfl(inv, (l&48) | ((g<<2)+ri), 64);
      const int q = q0w + (g<<2) + ri;
      #pragma unroll
      for (int dcb=0;dcb<8;dcb++)
        ctx[(((size_t)(b<<10) + q)<<11) + (h<<7) + (dcb<<4) + c] = (bf16)(o[dcb][ri]*iv);
    }
  }
}

// ---------------- launcher ----------------
extern "C" void kernel_launch(void* const* d_in, const int* in_sizes, int n_in,
                              void* d_out, int out_size, void* d_ws, size_t ws_size,
                              hipStream_t stream)
{
  const float* hidden  = (const float*)d_in[0];
  const float* W_attn  = (const float*)d_in[1];
  const float* b_attn  = (const float*)d_in[2];
  const float* W_proj  = (const float*)d_in[3];
  const float* b_proj  = (const float*)d_in[4];
  const float* k_pages = (const float*)d_in[5];
  const float* v_pages = (const float*)d_in[6];
  const int*   page_pos  = (const int*)d_in[7];
  const int*   input_pos = (const int*)d_in[8];
  float* out = (float*)d_out;
  char* ws = (char*)d_ws;
  bf16* A1  = (bf16*)(ws);              // 8192x2048 bf16 (32MB); reused as ctx
  bf16* Wt1 = (bf16*)(ws + 33554432);   // 6144x2048 bf16 (24MB)
  bf16* Wt2 = (bf16*)(ws + 58720256);   // 2048x2048 bf16 (8MB)
  bf16* qb  = (bf16*)(ws + 67108864);   // [8,16,1024,128] bf16 (32MB)
  bf16* kb  = (bf16*)(ws + 100663296);
  bf16* vb  = (bf16*)(ws + 134217728);  // end 167,772,160
  bf16* ctx = A1;

  k_pre<<<32768, 256, 0, stream>>>(hidden, A1, W_attn, Wt1, W_proj, Wt2);
  k_gemm8<0><<<768, 512, 0, stream>>>(A1, Wt1, b_attn, 6144, 2048, qb, kb, vb, nullptr);
  k_attn<<<1024, 512, 0, stream>>>(qb, kb, vb, k_pages, v_pages, page_pos, input_pos, ctx);
  k_gemm8<1><<<256, 512, 0, stream>>>(ctx, Wt2, b_proj, 2048, 2048, nullptr, nullptr, nullptr, out);
}